// Round 16
// baseline (893.041 us; speedup 1.0000x reference)
//
#include <hip/hip_runtime.h>
#include <hip/hip_cooperative_groups.h>

namespace cg = cooperative_groups;

#define HW 16384        // 128*128
#define PADPIX 16900    // 130*130 padded pixel count

typedef __attribute__((ext_vector_type(8))) short short8v;
typedef __attribute__((ext_vector_type(4))) float f32x4;

__device__ inline short bf16rne(float x) {
    unsigned u = __float_as_uint(x);
    unsigned r = (u + 0x7fffu + ((u >> 16) & 1u)) >> 16;
    return (short)r;
}
__device__ inline float bf16tof(short s) {
    return __uint_as_float(((unsigned)(unsigned short)s) << 16);
}

// padded-pixel index for border element j (j in 0..515)
__device__ inline int border_pp(int j) {
    if (j < 130) return j;                          // row 0
    if (j < 260) return 129 * 130 + (j - 130);      // row 129
    if (j < 388) return (j - 259) * 130;            // col 0, rows 1..128
    return (j - 387) * 130 + 129;                   // col 129, rows 1..128
}

#define UPSTR 72                 // ch-stride of upB in shorts (16B-aligned)
#define UPROW (34 * UPSTR)       // shorts per upB row (34 lpx)

// ===================== phase bodies as device functions ======================

__device__ __forceinline__ void wprep_body(int bid, int t,
    const float* __restrict__ W1, const float* __restrict__ W2,
    const float* __restrict__ Wk,
    short* __restrict__ Wb1, short* __restrict__ Wb2, short* __restrict__ Wbk)
{
    const float* W; short* Wb; int CIN, COUT, idx;
    if (bid < 288)      { W = W1; Wb = Wb1; CIN = 128; COUT = 64; idx = bid * 256 + t; }
    else if (bid < 432) { W = W2; Wb = Wb2; CIN = 64;  COUT = 64; idx = (bid - 288) * 256 + t; }
    else                { W = Wk; Wb = Wbk; CIN = 64;  COUT = 16; idx = (bid - 432) * 256 + t; }
    int NOCT = COUT >> 4, NCH = CIN >> 5;
    int total = 9 * NCH * NOCT * 512;
    if (idx < total) {
        int j = idx & 7, l = (idx >> 3) & 63;
        int rest = idx >> 9;
        int oct = rest % NOCT; rest /= NOCT;
        int ch = rest % NCH;
        int tap = rest / NCH;
        int o = oct * 16 + (l & 15);
        int c = ch * 32 + (l >> 4) * 8 + j;
        Wb[idx] = bf16rne(W[((size_t)o * CIN + c) * 9 + tap]);
    }
}

__device__ __forceinline__ void border_body(int t2,
    short* __restrict__ hcatN, short* __restrict__ h1N)
{
    const int4 z = make_int4(0, 0, 0, 0);
    if (t2 < 16512) {
        int px = t2 >> 4, q = t2 & 15;
        int b = px >= 516; int j = px - b * 516;
        int pp = border_pp(j);
        ((int4*)hcatN)[((size_t)b * PADPIX + pp) * 16 + q] = z;
    } else if (t2 < 24768) {
        int idx = t2 - 16512;
        int px = idx >> 3, q = idx & 7;
        int b = px >= 516; int j = px - b * 516;
        int pp = border_pp(j);
        ((int4*)h1N)[((size_t)b * PADPIX + pp) * 8 + q] = z;
    }
}

__device__ __forceinline__ void front_body(int bid, int t,
    short* upB, float* kfs, float* qbuf, int* tr,
    const float* __restrict__ x1, const short* __restrict__ Wbk,
    const float* __restrict__ bk, const float* __restrict__ Wq,
    const float* __restrict__ bq, const float* __restrict__ x2,
    const float* __restrict__ Wv, const float* __restrict__ bv,
    short* __restrict__ hcatN)
{
    const int xq = bid & 3;
    const int y = (bid >> 2) & 127;
    const int b = bid >> 9;
    const int X0 = xq * 32;

    // ---- phase 1: upsample rows y-1..y+1 (bf16) into upB, zeros outside ----
    {
        const int px1 = t & 31, cg1 = t >> 5;        // 32 px x 8 ch-groups
        const int gx = X0 + px1;
        float fx = (float)(gx * 63) / 127.f;
        int x0 = (int)fx; float wx = fx - (float)x0; int x1i = min(x0 + 1, 63);
        #pragma unroll
        for (int r = 0; r < 3; r++) {
            int ry = y + r - 1;
            bool rv = ((unsigned)ry < 128u);
            int ryc = rv ? ry : 0;
            float fy = (float)(ryc * 63) / 127.f;
            int y0 = (int)fy; float wy = fy - (float)y0; int y1 = min(y0 + 1, 63);
            int pk[4];
            #pragma unroll
            for (int jj = 0; jj < 4; jj++) {
                unsigned lohi[2];
                #pragma unroll
                for (int h = 0; h < 2; h++) {
                    int ch = cg1 * 8 + jj * 2 + h;
                    float v = 0.f;
                    if (rv) {
                        const float* sp = x1 + ((size_t)(b * 64 + ch) << 12);
                        float v00 = sp[(y0 << 6) + x0], v01 = sp[(y0 << 6) + x1i];
                        float v10 = sp[(y1 << 6) + x0], v11 = sp[(y1 << 6) + x1i];
                        float top = v00 * (1.f - wx) + v01 * wx;
                        float bot = v10 * (1.f - wx) + v11 * wx;
                        v = top * (1.f - wy) + bot * wy;
                    }
                    lohi[h] = (unsigned)(unsigned short)bf16rne(v);
                }
                pk[jj] = (int)(lohi[0] | (lohi[1] << 16));
            }
            *(int4*)(upB + r * UPROW + (px1 + 1) * UPSTR + cg1 * 8) =
                make_int4(pk[0], pk[1], pk[2], pk[3]);
        }
        if (t < 48) {                                // halo: r x side x cg
            int r = t >> 4, side = (t >> 3) & 1, cg2 = t & 7;
            int gxh = X0 + (side ? 32 : -1);
            int lpx = side ? 33 : 0;
            int ry = y + r - 1;
            bool v_ok = ((unsigned)ry < 128u) && ((unsigned)gxh < 128u);
            int ryc = ((unsigned)ry < 128u) ? ry : 0;
            float fy = (float)(ryc * 63) / 127.f;
            int y0 = (int)fy; float wy = fy - (float)y0; int y1 = min(y0 + 1, 63);
            int gxc = min(max(gxh, 0), 127);
            float fxh = (float)(gxc * 63) / 127.f;
            int hx0 = (int)fxh; float hwx = fxh - (float)hx0; int hx1 = min(hx0 + 1, 63);
            int pk[4];
            #pragma unroll
            for (int jj = 0; jj < 4; jj++) {
                unsigned lohi[2];
                #pragma unroll
                for (int h = 0; h < 2; h++) {
                    int ch = cg2 * 8 + jj * 2 + h;
                    float v = 0.f;
                    if (v_ok) {
                        const float* sp = x1 + ((size_t)(b * 64 + ch) << 12);
                        float v00 = sp[(y0 << 6) + hx0], v01 = sp[(y0 << 6) + hx1];
                        float v10 = sp[(y1 << 6) + hx0], v11 = sp[(y1 << 6) + hx1];
                        float top = v00 * (1.f - hwx) + v01 * hwx;
                        float bot = v10 * (1.f - hwx) + v11 * hwx;
                        v = top * (1.f - wy) + bot * wy;
                    }
                    lohi[h] = (unsigned)(unsigned short)bf16rne(v);
                }
                pk[jj] = (int)(lohi[0] | (lohi[1] << 16));
            }
            *(int4*)(upB + r * UPROW + lpx * UPSTR + cg2 * 8) =
                make_int4(pk[0], pk[1], pk[2], pk[3]);
        }
    }
    __syncthreads();

    // ---- phase 2: waves 0-1: Kf MFMA (16 px each); waves 2-3: qconv --------
    {
        const int w = t >> 6, l = t & 63;
        if (w < 2) {
            const int lx = l & 15, kg = l >> 4;
            const short* wbase = Wbk + (size_t)l * 8;
            f32x4 acc = (f32x4)(0.f);
            #pragma unroll
            for (int ty = 0; ty < 3; ty++) {
                #pragma unroll
                for (int tx = 0; tx < 3; tx++) {
                    const short* ab = upB + ty * UPROW + (size_t)(w * 16 + lx + tx) * UPSTR;
                    #pragma unroll
                    for (int ch = 0; ch < 2; ch++) {
                        short8v a = *(const short8v*)(ab + kg * 8 + ch * 32);
                        short8v bf = *(const short8v*)(wbase +
                            (size_t)((ty * 3 + tx) * 2 + ch) * 512);
                        acc = __builtin_amdgcn_mfma_f32_16x16x32_bf16(a, bf, acc, 0, 0, 0);
                    }
                }
            }
            float bb = bk[lx];
            #pragma unroll
            for (int r = 0; r < 4; r++)
                kfs[lx * 33 + (w * 16 + kg * 4 + r)] = fmaxf(acc[r] + bb, 0.f);
        } else {
            // depthwise qconv, ch-major sliding window (conflict-free LDS reads)
            const int ch = l;
            const int px0 = (w - 2) * 16;
            const float* wqp = Wq + ch * 9;
            float wq[9];
            #pragma unroll
            for (int i = 0; i < 9; i++) wq[i] = wqp[i];
            float bqc = bq[ch];
            float a0[3], a1[3];
            #pragma unroll
            for (int r = 0; r < 3; r++) {
                a0[r] = bf16tof(upB[r * UPROW + px0 * UPSTR + ch]);
                a1[r] = bf16tof(upB[r * UPROW + (px0 + 1) * UPSTR + ch]);
            }
            for (int p = 0; p < 16; p++) {
                float a2[3];
                #pragma unroll
                for (int r = 0; r < 3; r++)
                    a2[r] = bf16tof(upB[r * UPROW + (px0 + p + 2) * UPSTR + ch]);
                float q = bqc;
                #pragma unroll
                for (int r = 0; r < 3; r++)
                    q = fmaf(a0[r], wq[r * 3 + 0],
                        fmaf(a1[r], wq[r * 3 + 1], fmaf(a2[r], wq[r * 3 + 2], q)));
                qbuf[(px0 + p) * 65 + ch] = fmaxf(q, 0.f);
                #pragma unroll
                for (int r = 0; r < 3; r++) { a0[r] = a1[r]; a1[r] = a2[r]; }
            }
        }
    }
    __syncthreads();

    // ---- phase 3: softmax gate, 32 px x 64 ch -------------------------------
    {
        const int px = t & 31, cg3 = t >> 5;
        const int x = X0 + px;
        float kv[16];
        #pragma unroll
        for (int k = 0; k < 16; k++) kv[k] = kfs[k * 33 + px];
        float kvmax = kv[0];
        #pragma unroll
        for (int k = 1; k < 16; k++) kvmax = fmaxf(kvmax, kv[k]);
        float wvv[16], bvv[16];
        #pragma unroll
        for (int k = 0; k < 16; k++) { wvv[k] = Wv[k]; bvv[k] = bv[k]; }
        float xvv[8], qv[8];
        #pragma unroll
        for (int j = 0; j < 8; j++) {
            xvv[j] = x2[((size_t)(b * 64 + cg3 * 8 + j) << 14) + (y << 7) + x];
            qv[j] = qbuf[px * 65 + cg3 * 8 + j];
        }
        #pragma unroll
        for (int jj = 0; jj < 4; jj++) {
            int gpk = 0;
            #pragma unroll
            for (int h = 0; h < 2; h++) {
                const int j = jj * 2 + h;
                float q = qv[j];
                float mx = q * kvmax;                // q,kv >= 0 => exact max
                float den = 0.f, num = 0.f;
                #pragma unroll
                for (int k = 0; k < 16; k++) {
                    float e = __expf(fmaf(q, kv[k], -mx));
                    den += e;
                    float V = fmaxf(fmaf(xvv[j], wvv[k], bvv[k]), 0.f);
                    num = fmaf(e, V, num);
                }
                unsigned u = (unsigned)(unsigned short)bf16rne(num / den);
                gpk |= (int)(u << (h * 16));
            }
            tr[(cg3 * 4 + jj) * 33 + px] = gpk;
        }
    }
    __syncthreads();

    // ---- phase 4: coalesced writes: gate -> ch 0..63, upB row1 -> ch 64..127
    {
        const int px4 = t >> 3, cq = t & 7;
        int pp = (y + 1) * 130 + X0 + px4 + 1;
        int wd[4];
        #pragma unroll
        for (int i = 0; i < 4; i++) wd[i] = tr[(cq * 4 + i) * 33 + px4];
        int* dpL = (int*)hcatN + ((size_t)b * PADPIX + pp) * 64 + cq * 4;
        *(int4*)dpL = make_int4(wd[0], wd[1], wd[2], wd[3]);
        const short* us = upB + UPROW + (size_t)(px4 + 1) * UPSTR + cq * 8;
        int4 u = *(const int4*)us;
        int* dpU = (int*)hcatN + ((size_t)b * PADPIX + pp) * 64 + 32 + cq * 4;
        *(int4*)dpU = u;
    }
}

template<int PSTR, int CIN, int COUT, int NWN, int OPW, int MB>
__device__ __forceinline__ void conv_body(int B, int t,
    const short* __restrict__ actN, const short* __restrict__ Wb,
    float* __restrict__ dst, float* __restrict__ partials)
{
    constexpr int NCH = CIN / 32, NOCT = COUT / 16, NWM = 4 / NWN;
    constexpr int EXT = NWM * MB * 16;
    constexpr int SEG = 128 / EXT;
    const int w = t >> 6, l = t & 63;
    const int wn = w % NWN, wm = w / NWN;
    int bid = B;
    const int xseg = bid % SEG; bid /= SEG;
    const int y = bid & 127;
    const int b = bid >> 7;
    const int lx = l & 15, kg = l >> 4;
    const int x = xseg * EXT + wm * (MB * 16) + lx;

    const short* base = actN + ((size_t)b * PADPIX + (size_t)y * 130 + x) * PSTR + kg * 8;
    const short* wbase = Wb + (size_t)(wn * OPW) * 512 + (size_t)l * 8;

    f32x4 acc[MB][OPW];
    #pragma unroll
    for (int m = 0; m < MB; m++)
        #pragma unroll
        for (int p = 0; p < OPW; p++) acc[m][p] = (f32x4)(0.f);

    #pragma unroll
    for (int ty = 0; ty < 3; ty++) {
        #pragma unroll
        for (int tx = 0; tx < 3; tx++) {
            const short* ab = base + (ty * 130 + tx) * PSTR;
            const int tap = ty * 3 + tx;
            #pragma unroll
            for (int ch = 0; ch < NCH; ch++) {
                short8v a[MB];
                #pragma unroll
                for (int m = 0; m < MB; m++)
                    a[m] = *(const short8v*)(ab + m * 16 * PSTR + ch * 32);
                #pragma unroll
                for (int p = 0; p < OPW; p++) {
                    short8v bf = *(const short8v*)(wbase +
                        (size_t)((tap * NCH + ch) * NOCT + p) * 512);
                    #pragma unroll
                    for (int m = 0; m < MB; m++)
                        acc[m][p] = __builtin_amdgcn_mfma_f32_16x16x32_bf16(a[m], bf, acc[m][p], 0, 0, 0);
                }
            }
        }
    }

    #pragma unroll
    for (int m = 0; m < MB; m++) {
        const int ox = xseg * EXT + wm * (MB * 16) + m * 16 + kg * 4;
        #pragma unroll
        for (int p = 0; p < OPW; p++) {
            const int oc = (wn * OPW + p) * 16 + lx;
            *(f32x4*)(dst + (((size_t)(b * COUT + oc)) << 14) + (y << 7) + ox) = acc[m][p];
        }
    }

    // per-wave BN partials: shfl reduce, race-free plain stores
    #pragma unroll
    for (int p = 0; p < OPW; p++) {
        float s = 0.f, q2 = 0.f;
        #pragma unroll
        for (int m = 0; m < MB; m++) {
            f32x4 v = acc[m][p];
            #pragma unroll
            for (int r = 0; r < 4; r++) { s += v[r]; q2 = fmaf(v[r], v[r], q2); }
        }
        s += __shfl_xor(s, 16); q2 += __shfl_xor(q2, 16);
        s += __shfl_xor(s, 32); q2 += __shfl_xor(q2, 32);
        if (l < 16) {
            const int oc = (wn * OPW + p) * 16 + lx;
            float* dp = partials + (((size_t)B * NWM + wm) * 64 + oc) * 2;
            dp[0] = s;
            dp[1] = q2;
        }
    }
}

__device__ __forceinline__ void bnred_body(int ch, int t, float* sh,
    const float* __restrict__ partials, float* __restrict__ statsAcc)
{
    float s = 0.f, q = 0.f;
    for (int i = t; i < 2048; i += 256) {
        const float* p = partials + ((size_t)i * 64 + ch) * 2;
        s += p[0];
        q += p[1];
    }
    sh[t] = s;
    sh[256 + t] = q;
    __syncthreads();
    for (int off = 128; off > 0; off >>= 1) {
        if (t < off) {
            sh[t] += sh[t + off];
            sh[256 + t] += sh[256 + t + off];
        }
        __syncthreads();
    }
    if (t == 0) {
        statsAcc[ch * 2] = sh[0];
        statsAcc[ch * 2 + 1] = sh[256];
    }
}

__device__ __forceinline__ void packN_body(int bid, int t, int* lds,
    const float* __restrict__ src, const float* __restrict__ statsAcc,
    const float* __restrict__ g, const float* __restrict__ beta,
    short* __restrict__ h1N)
{
    const int pxt = bid & 255;
    const int b = bid >> 8;
    {
        const int cw = t >> 3, pg = t & 7;
        #pragma unroll
        for (int h = 0; h < 2; h++) {
            int c = cw * 2 + h;
            float mean = statsAcc[c * 2] * (1.f / 32768.f);
            float var  = statsAcc[c * 2 + 1] * (1.f / 32768.f) - mean * mean;
            float sc = g[c] * rsqrtf(var + 1e-5f);
            float sh = beta[c] - mean * sc;
            const float* sp = src + ((size_t)(b * 64 + c) << 14) + pxt * 64 + pg * 8;
            float4 v0 = *(const float4*)sp;
            float4 v1 = *(const float4*)(sp + 4);
            float vals[8] = {v0.x, v0.y, v0.z, v0.w, v1.x, v1.y, v1.z, v1.w};
            #pragma unroll
            for (int i = 0; i < 8; i++) {
                float v = fmaxf(fmaf(vals[i], sc, sh), 0.f);
                unsigned wv = (unsigned)(unsigned short)bf16rne(v);
                if (h == 0) lds[cw * 65 + pg * 8 + i] = (int)wv;
                else        lds[cw * 65 + pg * 8 + i] |= (int)(wv << 16);
            }
        }
    }
    __syncthreads();
    {
        const int px = t >> 2, cq = t & 3;
        int wd[8];
        #pragma unroll
        for (int i = 0; i < 8; i++) wd[i] = lds[(cq * 8 + i) * 65 + px];
        int pixel = pxt * 64 + px;
        int yy = pixel >> 7, xx = pixel & 127;
        int pp = (yy + 1) * 130 + xx + 1;
        int* dp = (int*)h1N + ((size_t)b * PADPIX + pp) * 32 + cq * 8;
        *(int4*)dp = make_int4(wd[0], wd[1], wd[2], wd[3]);
        *(int4*)(dp + 4) = make_int4(wd[4], wd[5], wd[6], wd[7]);
    }
}

__device__ __forceinline__ void norm2_body(int vb, int t,
    const float4* __restrict__ src, const float* __restrict__ statsAcc,
    const float* __restrict__ g, const float* __restrict__ beta,
    float4* __restrict__ out)
{
    int idx4 = vb * 256 + t;                             // over 2*64*4096
    int q = idx4 & 4095;
    int c = (idx4 >> 12) & 63;
    int b = idx4 >> 18;
    float mean = statsAcc[c * 2] * (1.f / 32768.f);
    float var  = statsAcc[c * 2 + 1] * (1.f / 32768.f) - mean * mean;
    float sc = g[c] * rsqrtf(var + 1e-5f);
    float sh = beta[c] - mean * sc;
    float4 v = src[idx4];
    v.x = fmaxf(fmaf(v.x, sc, sh), 0.f);
    v.y = fmaxf(fmaf(v.y, sc, sh), 0.f);
    v.z = fmaxf(fmaf(v.z, sc, sh), 0.f);
    v.w = fmaxf(fmaf(v.w, sc, sh), 0.f);
    int half = c >> 5, cc = c & 31;
    out[(size_t)half * 262144 + (((size_t)(b * 32 + cc)) << 12) + q] = v;
}

// ===================== cooperative mega-kernel ===============================
__global__ __launch_bounds__(256, 4) void mega_kernel(
    const float* x1, const float* x2,
    const float* Wq, const float* bq,
    const float* Wk, const float* bk,
    const float* Wv, const float* bv,
    const float* W1, const float* g1, const float* b1,
    const float* W2, const float* g2, const float* b2,
    float* out,
    float* c1out, float* stacc, short* hcatN, short* h1N,
    short* Wb1, short* Wb2, short* Wbk, float* partials)
{
    cg::grid_group grid = cg::this_grid();
    const int t = threadIdx.x;
    const int B = blockIdx.x;

    __shared__ __align__(16) char smem[29344];
    short* upB  = (short*)smem;                    // 14688 B
    float* kfs  = (float*)(smem + 14688);          //  2112 B
    float* qbuf = (float*)(smem + 16800);          //  8320 B
    int*   tr   = (int*)(smem + 25120);            //  4224 B
    int*   plds = (int*)smem;                      // packN: 8320 B
    float* rsh  = (float*)smem;                    // bnred: 2048 B

    // P0: weight prep (0..467) + borders (468..564)
    if (B < 468) wprep_body(B, t, W1, W2, Wk, Wb1, Wb2, Wbk);
    else if (B < 565) border_body((B - 468) * 256 + t, hcatN, h1N);
    grid.sync();

    // P1: front (all 1024 blocks)
    front_body(B, t, upB, kfs, qbuf, tr, x1, Wbk, bk, Wq, bq, x2, Wv, bv, hcatN);
    grid.sync();

    // P2: conv1 128->64 + partial stats
    conv_body<128, 128, 64, 2, 2, 1>(B, t, hcatN, Wb1, c1out, partials);
    grid.sync();

    // P3: BN1 reduce
    if (B < 64) bnred_body(B, t, rsh, partials, stacc);
    grid.sync();

    // P4: BN1 apply + relu + pack -> padded NHWC bf16
    if (B < 512) packN_body(B, t, plds, c1out, stacc, g1, b1, h1N);
    grid.sync();

    // P5: conv2 64->64 + partial stats
    conv_body<64, 64, 64, 2, 2, 1>(B, t, h1N, Wb2, c1out, partials);
    grid.sync();

    // P6: BN2 reduce
    if (B < 64) bnred_body(B, t, rsh, partials, stacc + 128);
    grid.sync();

    // P7: BN2 apply + relu + split -> d_out (2048 virtual blocks)
    norm2_body(B, t, (const float4*)c1out, stacc + 128, g2, b2, (float4*)out);
    norm2_body(B + 1024, t, (const float4*)c1out, stacc + 128, g2, b2, (float4*)out);
}

// ===================== fallback standalone kernels (round-15 proven) =========
__global__ __launch_bounds__(256) void k1_kernel(
    const float* __restrict__ W1, const float* __restrict__ W2,
    const float* __restrict__ Wk,
    short* __restrict__ Wb1, short* __restrict__ Wb2, short* __restrict__ Wbk,
    short* __restrict__ hcatN, short* __restrict__ h1N)
{
    int bid = blockIdx.x;
    if (bid < 468) wprep_body(bid, threadIdx.x, W1, W2, Wk, Wb1, Wb2, Wbk);
    else border_body((bid - 468) * 256 + threadIdx.x, hcatN, h1N);
}

__global__ __launch_bounds__(256) void front_kernel(
    const float* __restrict__ x1, const short* __restrict__ Wbk,
    const float* __restrict__ bk, const float* __restrict__ Wq,
    const float* __restrict__ bq, const float* __restrict__ x2,
    const float* __restrict__ Wv, const float* __restrict__ bv,
    short* __restrict__ hcatN)
{
    __shared__ __align__(16) char smem[29344];
    front_body(blockIdx.x, threadIdx.x,
               (short*)smem, (float*)(smem + 14688), (float*)(smem + 16800),
               (int*)(smem + 25120), x1, Wbk, bk, Wq, bq, x2, Wv, bv, hcatN);
}

template<int PSTR, int CIN, int COUT, int NWN, int OPW, int MB>
__global__ __launch_bounds__(256) void convmfma_kernel(
    const short* __restrict__ actN, const short* __restrict__ Wb,
    float* __restrict__ dst, float* __restrict__ partials)
{
    conv_body<PSTR, CIN, COUT, NWN, OPW, MB>(blockIdx.x, threadIdx.x,
                                             actN, Wb, dst, partials);
}

__global__ void bnred_kernel(const float* __restrict__ partials,
                             float* __restrict__ statsAcc) {
    __shared__ float sh[512];
    bnred_body(blockIdx.x, threadIdx.x, sh, partials, statsAcc);
}

__global__ __launch_bounds__(256) void packN_kernel(
    const float* __restrict__ src, const float* __restrict__ statsAcc,
    const float* __restrict__ g, const float* __restrict__ beta,
    short* __restrict__ h1N)
{
    __shared__ int lds[32 * 65];
    packN_body(blockIdx.x, threadIdx.x, lds, src, statsAcc, g, beta, h1N);
}

__global__ void norm2_kernel(const float4* __restrict__ src,
                             const float* __restrict__ statsAcc,
                             const float* __restrict__ g, const float* __restrict__ beta,
                             float4* __restrict__ out) {
    norm2_body(blockIdx.x, threadIdx.x, src, statsAcc, g, beta, out);
}

extern "C" void kernel_launch(void* const* d_in, const int* in_sizes, int n_in,
                              void* d_out, int out_size, void* d_ws, size_t ws_size,
                              hipStream_t stream) {
    const float* x1 = (const float*)d_in[0];
    // d_in[1] (x1_) is unused by the reference
    const float* x2 = (const float*)d_in[2];
    const float* Wq = (const float*)d_in[3];
    const float* bq = (const float*)d_in[4];
    const float* Wk = (const float*)d_in[5];
    const float* bk = (const float*)d_in[6];
    const float* Wv = (const float*)d_in[7];
    const float* bv = (const float*)d_in[8];
    const float* W1 = (const float*)d_in[9];
    const float* g1 = (const float*)d_in[10];
    const float* b1 = (const float*)d_in[11];
    const float* W2 = (const float*)d_in[12];
    const float* g2 = (const float*)d_in[13];
    const float* b2 = (const float*)d_in[14];
    float* out = (float*)d_out;
    float* ws = (float*)d_ws;

    // workspace layout (float offsets)
    float* c1out    = ws;                        // [2][64][HW] fp32     (2,097,152)
    float* stacc    = ws + 2097152;              // 256 raw sums
    short* hcatN    = (short*)(ws + 2097408);    // [2][PADPIX][128] bf16 (2,163,200 f)
    short* h1N      = (short*)(ws + 4260608);    // [2][PADPIX][64]  bf16 (1,081,600 f)
    short* Wb1      = (short*)(ws + 5342208);    // 73728 shorts = 36864 f
    short* Wb2      = (short*)(ws + 5379072);    // 36864 shorts = 18432 f
    short* Wbk      = (short*)(ws + 5397504);    // 9216 shorts  =  4608 f
    float* partials = ws + 5402112;              // 2048*64*2 = 262,144 f (1 MB)

    void* args[] = {
        (void*)&x1, (void*)&x2, (void*)&Wq, (void*)&bq, (void*)&Wk, (void*)&bk,
        (void*)&Wv, (void*)&bv, (void*)&W1, (void*)&g1, (void*)&b1,
        (void*)&W2, (void*)&g2, (void*)&b2, (void*)&out,
        (void*)&c1out, (void*)&stacc, (void*)&hcatN, (void*)&h1N,
        (void*)&Wb1, (void*)&Wb2, (void*)&Wbk, (void*)&partials
    };
    hipError_t err = hipLaunchCooperativeKernel(
        (const void*)mega_kernel, dim3(1024), dim3(256), args, 0, stream);

    if (err != hipSuccess) {
        // fallback: identical math as 8 separate launches (round-15 proven)
        k1_kernel<<<565, 256, 0, stream>>>(W1, W2, Wk, Wb1, Wb2, Wbk, hcatN, h1N);
        front_kernel<<<1024, 256, 0, stream>>>(x1, Wbk, bk, Wq, bq, x2, Wv, bv, hcatN);
        convmfma_kernel<128, 128, 64, 2, 2, 1><<<1024, 256, 0, stream>>>(
            hcatN, Wb1, c1out, partials);
        bnred_kernel<<<64, 256, 0, stream>>>(partials, stacc);
        packN_kernel<<<512, 256, 0, stream>>>(c1out, stacc, g1, b1, h1N);
        convmfma_kernel<64, 64, 64, 2, 2, 1><<<1024, 256, 0, stream>>>(
            h1N, Wb2, c1out, partials);
        bnred_kernel<<<64, 256, 0, stream>>>(partials, stacc + 128);
        norm2_kernel<<<2048, 256, 0, stream>>>((const float4*)c1out, stacc + 128,
                                               g2, b2, (float4*)out);
    }
}

// Round 17
// 93.122 us; speedup vs baseline: 9.5901x; 9.5901x over previous
//
#include <hip/hip_runtime.h>

#define HW 16384        // 128*128
#define PADPIX 16900    // 130*130 padded pixel count

typedef __attribute__((ext_vector_type(8))) short short8v;
typedef __attribute__((ext_vector_type(4))) float f32x4;

__device__ inline short bf16rne(float x) {
    unsigned u = __float_as_uint(x);
    unsigned r = (u + 0x7fffu + ((u >> 16) & 1u)) >> 16;
    return (short)r;
}
__device__ inline float bf16tof(short s) {
    return __uint_as_float(((unsigned)(unsigned short)s) << 16);
}

// padded-pixel index for border element j (j in 0..515)
__device__ inline int border_pp(int j) {
    if (j < 130) return j;                          // row 0
    if (j < 260) return 129 * 130 + (j - 130);      // row 129
    if (j < 388) return (j - 259) * 130;            // col 0, rows 1..128
    return (j - 387) * 130 + 129;                   // col 129, rows 1..128
}

// ===== K1: weight prep (0..467) + borders (468..564) + stats zero (565) ======
__global__ __launch_bounds__(256) void k1_kernel(
    const float* __restrict__ W1, const float* __restrict__ W2,
    const float* __restrict__ Wk,
    short* __restrict__ Wb1, short* __restrict__ Wb2, short* __restrict__ Wbk,
    short* __restrict__ hcatN, short* __restrict__ h1N,
    float* __restrict__ statsAcc)
{
    int bid = blockIdx.x;
    const int t = threadIdx.x;
    if (bid == 565) {
        statsAcc[t] = 0.f;                           // 256 floats (harmless)
        return;
    }
    if (bid < 468) {
        const float* W; short* Wb; int CIN, COUT, idx;
        if (bid < 288)      { W = W1; Wb = Wb1; CIN = 128; COUT = 64; idx = bid * 256 + t; }
        else if (bid < 432) { W = W2; Wb = Wb2; CIN = 64;  COUT = 64; idx = (bid - 288) * 256 + t; }
        else                { W = Wk; Wb = Wbk; CIN = 64;  COUT = 16; idx = (bid - 432) * 256 + t; }
        int NOCT = COUT >> 4, NCH = CIN >> 5;
        int total = 9 * NCH * NOCT * 512;
        if (idx >= total) return;
        int j = idx & 7, l = (idx >> 3) & 63;
        int rest = idx >> 9;
        int oct = rest % NOCT; rest /= NOCT;
        int ch = rest % NCH;
        int tap = rest / NCH;
        int o = oct * 16 + (l & 15);
        int c = ch * 32 + (l >> 4) * 8 + j;
        Wb[idx] = bf16rne(W[((size_t)o * CIN + c) * 9 + tap]);
        return;
    }
    // ---- zero borders of hcatN (16512 int4) and h1N (8256 int4) ----
    int t2 = (bid - 468) * 256 + t;
    const int4 z = make_int4(0, 0, 0, 0);
    if (t2 < 16512) {
        int px = t2 >> 4, q = t2 & 15;
        int b = px >= 516; int j = px - b * 516;
        int pp = border_pp(j);
        ((int4*)hcatN)[((size_t)b * PADPIX + pp) * 16 + q] = z;
    } else if (t2 < 24768) {
        int idx = t2 - 16512;
        int px = idx >> 3, q = idx & 7;
        int b = px >= 516; int j = px - b * 516;
        int pp = border_pp(j);
        ((int4*)h1N)[((size_t)b * PADPIX + pp) * 8 + q] = z;
    }
}

// ===== front: upsample -> (Kf MFMA || qconv) -> gate -> hcatN, all in LDS ====
#define UPSTR 72                 // ch-stride of upB in shorts (16B-aligned)
#define UPROW (34 * UPSTR)       // shorts per upB row (34 lpx)
__global__ __launch_bounds__(256) void front_kernel(
    const float* __restrict__ x1, const short* __restrict__ Wbk,
    const float* __restrict__ bk, const float* __restrict__ Wq,
    const float* __restrict__ bq, const float* __restrict__ x2,
    const float* __restrict__ Wv, const float* __restrict__ bv,
    short* __restrict__ hcatN)
{
    __shared__ __align__(16) short upB[3 * UPROW];   // [r][lpx 0..33][ch 0..63]
    __shared__ float kfs[16 * 33];                   // [k][px 0..31], stride 33
    __shared__ float qbuf[32 * 65];                  // [px][ch], stride 65
    __shared__ int tr[32 * 33];                      // [chpair][px], stride 33
    int bid = blockIdx.x;
    const int xq = bid & 3;
    const int y = (bid >> 2) & 127;
    const int b = bid >> 9;
    const int t = threadIdx.x;
    const int X0 = xq * 32;

    // ---- phase 1: upsample rows y-1..y+1 (bf16) into upB, zeros outside ----
    {
        const int px1 = t & 31, cg1 = t >> 5;        // 32 px x 8 ch-groups
        const int gx = X0 + px1;
        float fx = (float)(gx * 63) / 127.f;
        int x0 = (int)fx; float wx = fx - (float)x0; int x1i = min(x0 + 1, 63);
        #pragma unroll
        for (int r = 0; r < 3; r++) {
            int ry = y + r - 1;
            bool rv = ((unsigned)ry < 128u);
            int ryc = rv ? ry : 0;
            float fy = (float)(ryc * 63) / 127.f;
            int y0 = (int)fy; float wy = fy - (float)y0; int y1 = min(y0 + 1, 63);
            int pk[4];
            #pragma unroll
            for (int jj = 0; jj < 4; jj++) {
                unsigned lohi[2];
                #pragma unroll
                for (int h = 0; h < 2; h++) {
                    int ch = cg1 * 8 + jj * 2 + h;
                    float v = 0.f;
                    if (rv) {
                        const float* sp = x1 + ((size_t)(b * 64 + ch) << 12);
                        float v00 = sp[(y0 << 6) + x0], v01 = sp[(y0 << 6) + x1i];
                        float v10 = sp[(y1 << 6) + x0], v11 = sp[(y1 << 6) + x1i];
                        float top = v00 * (1.f - wx) + v01 * wx;
                        float bot = v10 * (1.f - wx) + v11 * wx;
                        v = top * (1.f - wy) + bot * wy;
                    }
                    lohi[h] = (unsigned)(unsigned short)bf16rne(v);
                }
                pk[jj] = (int)(lohi[0] | (lohi[1] << 16));
            }
            *(int4*)(upB + r * UPROW + (px1 + 1) * UPSTR + cg1 * 8) =
                make_int4(pk[0], pk[1], pk[2], pk[3]);
        }
        if (t < 48) {                                // halo: r x side x cg
            int r = t >> 4, side = (t >> 3) & 1, cg = t & 7;
            int gxh = X0 + (side ? 32 : -1);
            int lpx = side ? 33 : 0;
            int ry = y + r - 1;
            bool v_ok = ((unsigned)ry < 128u) && ((unsigned)gxh < 128u);
            int ryc = ((unsigned)ry < 128u) ? ry : 0;
            float fy = (float)(ryc * 63) / 127.f;
            int y0 = (int)fy; float wy = fy - (float)y0; int y1 = min(y0 + 1, 63);
            int gxc = min(max(gxh, 0), 127);
            float fxh = (float)(gxc * 63) / 127.f;
            int hx0 = (int)fxh; float hwx = fxh - (float)hx0; int hx1 = min(hx0 + 1, 63);
            int pk[4];
            #pragma unroll
            for (int jj = 0; jj < 4; jj++) {
                unsigned lohi[2];
                #pragma unroll
                for (int h = 0; h < 2; h++) {
                    int ch = cg * 8 + jj * 2 + h;
                    float v = 0.f;
                    if (v_ok) {
                        const float* sp = x1 + ((size_t)(b * 64 + ch) << 12);
                        float v00 = sp[(y0 << 6) + hx0], v01 = sp[(y0 << 6) + hx1];
                        float v10 = sp[(y1 << 6) + hx0], v11 = sp[(y1 << 6) + hx1];
                        float top = v00 * (1.f - hwx) + v01 * hwx;
                        float bot = v10 * (1.f - hwx) + v11 * hwx;
                        v = top * (1.f - wy) + bot * wy;
                    }
                    lohi[h] = (unsigned)(unsigned short)bf16rne(v);
                }
                pk[jj] = (int)(lohi[0] | (lohi[1] << 16));
            }
            *(int4*)(upB + r * UPROW + lpx * UPSTR + cg * 8) =
                make_int4(pk[0], pk[1], pk[2], pk[3]);
        }
    }
    __syncthreads();

    // ---- phase 2: waves 0-1: Kf MFMA (16 px each); waves 2-3: qconv --------
    {
        const int w = t >> 6, l = t & 63;
        if (w < 2) {
            const int lx = l & 15, kg = l >> 4;
            const short* wbase = Wbk + (size_t)l * 8;
            f32x4 acc = (f32x4)(0.f);
            #pragma unroll
            for (int ty = 0; ty < 3; ty++) {
                #pragma unroll
                for (int tx = 0; tx < 3; tx++) {
                    const short* ab = upB + ty * UPROW + (size_t)(w * 16 + lx + tx) * UPSTR;
                    #pragma unroll
                    for (int ch = 0; ch < 2; ch++) {
                        short8v a = *(const short8v*)(ab + kg * 8 + ch * 32);
                        short8v bf = *(const short8v*)(wbase +
                            (size_t)((ty * 3 + tx) * 2 + ch) * 512);
                        acc = __builtin_amdgcn_mfma_f32_16x16x32_bf16(a, bf, acc, 0, 0, 0);
                    }
                }
            }
            float bb = bk[lx];
            #pragma unroll
            for (int r = 0; r < 4; r++)
                kfs[lx * 33 + (w * 16 + kg * 4 + r)] = fmaxf(acc[r] + bb, 0.f);
        } else {
            // depthwise qconv, ch-major sliding window (conflict-free LDS reads)
            const int ch = l;
            const int px0 = (w - 2) * 16;
            const float* wqp = Wq + ch * 9;
            float wq[9];
            #pragma unroll
            for (int i = 0; i < 9; i++) wq[i] = wqp[i];
            float bqc = bq[ch];
            float a0[3], a1[3];
            #pragma unroll
            for (int r = 0; r < 3; r++) {
                a0[r] = bf16tof(upB[r * UPROW + px0 * UPSTR + ch]);
                a1[r] = bf16tof(upB[r * UPROW + (px0 + 1) * UPSTR + ch]);
            }
            for (int p = 0; p < 16; p++) {
                float a2[3];
                #pragma unroll
                for (int r = 0; r < 3; r++)
                    a2[r] = bf16tof(upB[r * UPROW + (px0 + p + 2) * UPSTR + ch]);
                float q = bqc;
                #pragma unroll
                for (int r = 0; r < 3; r++)
                    q = fmaf(a0[r], wq[r * 3 + 0],
                        fmaf(a1[r], wq[r * 3 + 1], fmaf(a2[r], wq[r * 3 + 2], q)));
                qbuf[(px0 + p) * 65 + ch] = fmaxf(q, 0.f);
                #pragma unroll
                for (int r = 0; r < 3; r++) { a0[r] = a1[r]; a1[r] = a2[r]; }
            }
        }
    }
    __syncthreads();

    // ---- phase 3: softmax gate, 32 px x 64 ch -------------------------------
    {
        const int px = t & 31, cg = t >> 5;
        const int x = X0 + px;
        float kv[16];
        #pragma unroll
        for (int k = 0; k < 16; k++) kv[k] = kfs[k * 33 + px];
        float kvmax = kv[0];
        #pragma unroll
        for (int k = 1; k < 16; k++) kvmax = fmaxf(kvmax, kv[k]);
        float wvv[16], bvv[16];
        #pragma unroll
        for (int k = 0; k < 16; k++) { wvv[k] = Wv[k]; bvv[k] = bv[k]; }
        float xvv[8], qv[8];
        #pragma unroll
        for (int j = 0; j < 8; j++) {
            xvv[j] = x2[((size_t)(b * 64 + cg * 8 + j) << 14) + (y << 7) + x];
            qv[j] = qbuf[px * 65 + cg * 8 + j];
        }
        #pragma unroll
        for (int jj = 0; jj < 4; jj++) {
            int gpk = 0;
            #pragma unroll
            for (int h = 0; h < 2; h++) {
                const int j = jj * 2 + h;
                float q = qv[j];
                float mx = q * kvmax;                // q,kv >= 0 => exact max
                float den = 0.f, num = 0.f;
                #pragma unroll
                for (int k = 0; k < 16; k++) {
                    float e = __expf(fmaf(q, kv[k], -mx));
                    den += e;
                    float V = fmaxf(fmaf(xvv[j], wvv[k], bvv[k]), 0.f);
                    num = fmaf(e, V, num);
                }
                unsigned u = (unsigned)(unsigned short)bf16rne(num / den);
                gpk |= (int)(u << (h * 16));
            }
            tr[(cg * 4 + jj) * 33 + px] = gpk;
        }
    }
    __syncthreads();

    // ---- phase 4: coalesced writes: gate -> ch 0..63, upB row1 -> ch 64..127
    {
        const int px4 = t >> 3, cq = t & 7;
        int pp = (y + 1) * 130 + X0 + px4 + 1;
        int wd[4];
        #pragma unroll
        for (int i = 0; i < 4; i++) wd[i] = tr[(cq * 4 + i) * 33 + px4];
        int* dpL = (int*)hcatN + ((size_t)b * PADPIX + pp) * 64 + cq * 4;
        *(int4*)dpL = make_int4(wd[0], wd[1], wd[2], wd[3]);
        const short* us = upB + UPROW + (size_t)(px4 + 1) * UPSTR + cq * 8;
        int4 u = *(const int4*)us;
        int* dpU = (int*)hcatN + ((size_t)b * PADPIX + pp) * 64 + 32 + cq * 4;
        *(int4*)dpU = u;
    }
}

// ===== MFMA implicit-GEMM 3x3 conv + race-free partial-stat stores ===========
// Each wave's (s, sumsq) goes to a UNIQUE address (bid, wm, oc) — no atomics.
template<int PSTR, int CIN, int COUT, int NWN, int OPW, int MB>
__global__ __launch_bounds__(256) void convmfma_kernel(
    const short* __restrict__ actN, const short* __restrict__ Wb,
    float* __restrict__ dst, float* __restrict__ partials)
{
    constexpr int NCH = CIN / 32, NOCT = COUT / 16, NWM = 4 / NWN;
    constexpr int EXT = NWM * MB * 16;
    constexpr int SEG = 128 / EXT;
    const int t = threadIdx.x;
    const int w = t >> 6, l = t & 63;
    const int wn = w % NWN, wm = w / NWN;
    int bid = blockIdx.x;
    const int xseg = bid % SEG; bid /= SEG;
    const int y = bid & 127;
    const int b = bid >> 7;
    const int lx = l & 15, kg = l >> 4;
    const int x = xseg * EXT + wm * (MB * 16) + lx;

    const short* base = actN + ((size_t)b * PADPIX + (size_t)y * 130 + x) * PSTR + kg * 8;
    const short* wbase = Wb + (size_t)(wn * OPW) * 512 + (size_t)l * 8;

    f32x4 acc[MB][OPW];
    #pragma unroll
    for (int m = 0; m < MB; m++)
        #pragma unroll
        for (int p = 0; p < OPW; p++) acc[m][p] = (f32x4)(0.f);

    #pragma unroll
    for (int ty = 0; ty < 3; ty++) {
        #pragma unroll
        for (int tx = 0; tx < 3; tx++) {
            const short* ab = base + (ty * 130 + tx) * PSTR;
            const int tap = ty * 3 + tx;
            #pragma unroll
            for (int ch = 0; ch < NCH; ch++) {
                short8v a[MB];
                #pragma unroll
                for (int m = 0; m < MB; m++)
                    a[m] = *(const short8v*)(ab + m * 16 * PSTR + ch * 32);
                #pragma unroll
                for (int p = 0; p < OPW; p++) {
                    short8v bf = *(const short8v*)(wbase +
                        (size_t)((tap * NCH + ch) * NOCT + p) * 512);
                    #pragma unroll
                    for (int m = 0; m < MB; m++)
                        acc[m][p] = __builtin_amdgcn_mfma_f32_16x16x32_bf16(a[m], bf, acc[m][p], 0, 0, 0);
                }
            }
        }
    }

    #pragma unroll
    for (int m = 0; m < MB; m++) {
        const int ox = xseg * EXT + wm * (MB * 16) + m * 16 + kg * 4;
        #pragma unroll
        for (int p = 0; p < OPW; p++) {
            const int oc = (wn * OPW + p) * 16 + lx;
            *(f32x4*)(dst + (((size_t)(b * COUT + oc)) << 14) + (y << 7) + ox) = acc[m][p];
        }
    }

    // per-wave BN partials: shfl reduce over the 4 kg groups, plain stores
    #pragma unroll
    for (int p = 0; p < OPW; p++) {
        float s = 0.f, q2 = 0.f;
        #pragma unroll
        for (int m = 0; m < MB; m++) {
            f32x4 v = acc[m][p];
            #pragma unroll
            for (int r = 0; r < 4; r++) { s += v[r]; q2 = fmaf(v[r], v[r], q2); }
        }
        s += __shfl_xor(s, 16); q2 += __shfl_xor(q2, 16);
        s += __shfl_xor(s, 32); q2 += __shfl_xor(q2, 32);
        if (l < 16) {
            const int oc = (wn * OPW + p) * 16 + lx;
            float* dp = partials + (((size_t)blockIdx.x * NWM + wm) * 64 + oc) * 2;
            dp[0] = s;
            dp[1] = q2;
        }
    }
}

// ===== reduce 2048 partial pairs per channel -> raw sums (no atomics) ========
__global__ void bnred_kernel(const float* __restrict__ partials,
                             float* __restrict__ statsAcc) {
    int ch = blockIdx.x;                                 // 64 blocks
    const int t = threadIdx.x;
    float s = 0.f, q = 0.f;
    for (int i = t; i < 2048; i += 256) {
        const float* p = partials + ((size_t)i * 64 + ch) * 2;
        s += p[0];
        q += p[1];
    }
    __shared__ float sh[512];
    sh[t] = s;
    sh[256 + t] = q;
    __syncthreads();
    for (int off = 128; off > 0; off >>= 1) {
        if (t < off) {
            sh[t] += sh[t + off];
            sh[256 + t] += sh[256 + t + off];
        }
        __syncthreads();
    }
    if (t == 0) {
        statsAcc[ch * 2] = sh[0];
        statsAcc[ch * 2 + 1] = sh[256];
    }
}

// ===== NCHW fp32 -> padded NHWC bf16 with inline-finalized BN + relu =========
__global__ __launch_bounds__(256) void packN_kernel(
    const float* __restrict__ src, const float* __restrict__ statsAcc,
    const float* __restrict__ g, const float* __restrict__ beta,
    short* __restrict__ h1N)
{
    __shared__ int lds[32 * 65];
    int bid = blockIdx.x;
    const int pxt = bid & 255;
    const int b = bid >> 8;
    const int t = threadIdx.x;
    {
        const int cw = t >> 3, pg = t & 7;
        #pragma unroll
        for (int h = 0; h < 2; h++) {
            int c = cw * 2 + h;
            float mean = statsAcc[c * 2] * (1.f / 32768.f);
            float var  = statsAcc[c * 2 + 1] * (1.f / 32768.f) - mean * mean;
            float sc = g[c] * rsqrtf(var + 1e-5f);
            float sh = beta[c] - mean * sc;
            const float* sp = src + ((size_t)(b * 64 + c) << 14) + pxt * 64 + pg * 8;
            float4 v0 = *(const float4*)sp;
            float4 v1 = *(const float4*)(sp + 4);
            float vals[8] = {v0.x, v0.y, v0.z, v0.w, v1.x, v1.y, v1.z, v1.w};
            #pragma unroll
            for (int i = 0; i < 8; i++) {
                float v = fmaxf(fmaf(vals[i], sc, sh), 0.f);
                unsigned wv = (unsigned)(unsigned short)bf16rne(v);
                if (h == 0) lds[cw * 65 + pg * 8 + i] = (int)wv;
                else        lds[cw * 65 + pg * 8 + i] |= (int)(wv << 16);
            }
        }
    }
    __syncthreads();
    {
        const int px = t >> 2, cq = t & 3;
        int wd[8];
        #pragma unroll
        for (int i = 0; i < 8; i++) wd[i] = lds[(cq * 8 + i) * 65 + px];
        int pixel = pxt * 64 + px;
        int yy = pixel >> 7, xx = pixel & 127;
        int pp = (yy + 1) * 130 + xx + 1;
        int* dp = (int*)h1N + ((size_t)b * PADPIX + pp) * 32 + cq * 8;
        *(int4*)dp = make_int4(wd[0], wd[1], wd[2], wd[3]);
        *(int4*)(dp + 4) = make_int4(wd[4], wd[5], wd[6], wd[7]);
    }
}

// ===== inline-finalized BN + relu + split o1/o2 -> d_out =====================
__global__ void norm2_kernel(const float4* __restrict__ src,
                             const float* __restrict__ statsAcc,
                             const float* __restrict__ g, const float* __restrict__ beta,
                             float4* __restrict__ out) {
    int idx4 = blockIdx.x * 256 + threadIdx.x;           // over 2*64*4096
    int q = idx4 & 4095;
    int c = (idx4 >> 12) & 63;
    int b = idx4 >> 18;
    float mean = statsAcc[c * 2] * (1.f / 32768.f);
    float var  = statsAcc[c * 2 + 1] * (1.f / 32768.f) - mean * mean;
    float sc = g[c] * rsqrtf(var + 1e-5f);
    float sh = beta[c] - mean * sc;
    float4 v = src[idx4];
    v.x = fmaxf(fmaf(v.x, sc, sh), 0.f);
    v.y = fmaxf(fmaf(v.y, sc, sh), 0.f);
    v.z = fmaxf(fmaf(v.z, sc, sh), 0.f);
    v.w = fmaxf(fmaf(v.w, sc, sh), 0.f);
    int half = c >> 5, cc = c & 31;
    out[(size_t)half * 262144 + (((size_t)(b * 32 + cc)) << 12) + q] = v;
}

extern "C" void kernel_launch(void* const* d_in, const int* in_sizes, int n_in,
                              void* d_out, int out_size, void* d_ws, size_t ws_size,
                              hipStream_t stream) {
    const float* x1 = (const float*)d_in[0];
    // d_in[1] (x1_) is unused by the reference
    const float* x2 = (const float*)d_in[2];
    const float* Wq = (const float*)d_in[3];
    const float* bq = (const float*)d_in[4];
    const float* Wk = (const float*)d_in[5];
    const float* bk = (const float*)d_in[6];
    const float* Wv = (const float*)d_in[7];
    const float* bv = (const float*)d_in[8];
    const float* W1 = (const float*)d_in[9];
    const float* g1 = (const float*)d_in[10];
    const float* b1 = (const float*)d_in[11];
    const float* W2 = (const float*)d_in[12];
    const float* g2 = (const float*)d_in[13];
    const float* b2 = (const float*)d_in[14];
    float* out = (float*)d_out;
    float* ws = (float*)d_ws;

    // workspace layout (float offsets)
    float* c1out    = ws;                        // [2][64][HW] fp32     (2,097,152)
    float* stacc    = ws + 2097152;              // 256 raw sums (s1 @ +0, s2 @ +128)
    short* hcatN    = (short*)(ws + 2097408);    // [2][PADPIX][128] bf16 (2,163,200 f)
    short* h1N      = (short*)(ws + 4260608);    // [2][PADPIX][64]  bf16 (1,081,600 f)
    short* Wb1      = (short*)(ws + 5342208);    // 73728 shorts = 36864 f
    short* Wb2      = (short*)(ws + 5379072);    // 36864 shorts = 18432 f
    short* Wbk      = (short*)(ws + 5397504);    // 9216 shorts  =  4608 f
    float* partials = ws + 5402112;              // 1024*2*64*2 = 262,144 f (1 MB)

    // K1: weight prep + border zeroing + stats zero
    k1_kernel<<<566, 256, 0, stream>>>(W1, W2, Wk, Wb1, Wb2, Wbk, hcatN, h1N, stacc);

    // front: upsample + Kf conv + qconv + gate, fused -> hcatN (both halves)
    front_kernel<<<1024, 256, 0, stream>>>(x1, Wbk, bk, Wq, bq, x2, Wv, bv, hcatN);

    // conv1 128->64 + partial stats (plain stores)
    convmfma_kernel<128, 128, 64, 2, 2, 1><<<1024, 256, 0, stream>>>(
        hcatN, Wb1, c1out, partials);
    bnred_kernel<<<64, 256, 0, stream>>>(partials, stacc);
    packN_kernel<<<512, 256, 0, stream>>>(c1out, stacc, g1, b1, h1N);

    // conv2 64->64 + partial stats (plain stores, buffer reused sequentially)
    convmfma_kernel<64, 64, 64, 2, 2, 1><<<1024, 256, 0, stream>>>(
        h1N, Wb2, c1out, partials);
    bnred_kernel<<<64, 256, 0, stream>>>(partials, stacc + 128);
    norm2_kernel<<<2048, 256, 0, stream>>>((const float4*)c1out, stacc + 128, g2, b2,
                                           (float4*)out);
}

// Round 18
// 75.713 us; speedup vs baseline: 11.7952x; 1.2299x over previous
//
#include <hip/hip_runtime.h>

#define HW 16384        // 128*128
#define PADPIX 16900    // 130*130 padded pixel count

typedef __attribute__((ext_vector_type(8))) short short8v;
typedef __attribute__((ext_vector_type(4))) float f32x4;

__device__ inline short bf16rne(float x) {
    unsigned u = __float_as_uint(x);
    unsigned r = (u + 0x7fffu + ((u >> 16) & 1u)) >> 16;
    return (short)r;
}
__device__ inline float bf16tof(short s) {
    return __uint_as_float(((unsigned)(unsigned short)s) << 16);
}

// padded-pixel index for border element j (j in 0..515)
__device__ inline int border_pp(int j) {
    if (j < 130) return j;                          // row 0
    if (j < 260) return 129 * 130 + (j - 130);      // row 129
    if (j < 388) return (j - 259) * 130;            // col 0, rows 1..128
    return (j - 387) * 130 + 129;                   // col 129, rows 1..128
}

// ===== K1: weight prep (0..467) + borders (468..564) + stats zero (565) ======
__global__ __launch_bounds__(256) void k1_kernel(
    const float* __restrict__ W1, const float* __restrict__ W2,
    const float* __restrict__ Wk,
    short* __restrict__ Wb1, short* __restrict__ Wb2, short* __restrict__ Wbk,
    short* __restrict__ hcatN, short* __restrict__ h1N,
    float* __restrict__ statsAcc)
{
    int bid = blockIdx.x;
    const int t = threadIdx.x;
    if (bid == 565) {
        statsAcc[t] = 0.f;                           // 256 floats (harmless)
        return;
    }
    if (bid < 468) {
        const float* W; short* Wb; int CIN, COUT, idx;
        if (bid < 288)      { W = W1; Wb = Wb1; CIN = 128; COUT = 64; idx = bid * 256 + t; }
        else if (bid < 432) { W = W2; Wb = Wb2; CIN = 64;  COUT = 64; idx = (bid - 288) * 256 + t; }
        else                { W = Wk; Wb = Wbk; CIN = 64;  COUT = 16; idx = (bid - 432) * 256 + t; }
        int NOCT = COUT >> 4, NCH = CIN >> 5;
        int total = 9 * NCH * NOCT * 512;
        if (idx >= total) return;
        int j = idx & 7, l = (idx >> 3) & 63;
        int rest = idx >> 9;
        int oct = rest % NOCT; rest /= NOCT;
        int ch = rest % NCH;
        int tap = rest / NCH;
        int o = oct * 16 + (l & 15);
        int c = ch * 32 + (l >> 4) * 8 + j;
        Wb[idx] = bf16rne(W[((size_t)o * CIN + c) * 9 + tap]);
        return;
    }
    // ---- zero borders of hcatN (16512 int4) and h1N (8256 int4) ----
    int t2 = (bid - 468) * 256 + t;
    const int4 z = make_int4(0, 0, 0, 0);
    if (t2 < 16512) {
        int px = t2 >> 4, q = t2 & 15;
        int b = px >= 516; int j = px - b * 516;
        int pp = border_pp(j);
        ((int4*)hcatN)[((size_t)b * PADPIX + pp) * 16 + q] = z;
    } else if (t2 < 24768) {
        int idx = t2 - 16512;
        int px = idx >> 3, q = idx & 7;
        int b = px >= 516; int j = px - b * 516;
        int pp = border_pp(j);
        ((int4*)h1N)[((size_t)b * PADPIX + pp) * 8 + q] = z;
    }
}

// ===== front: upsample -> (Kf MFMA || qconv) -> gate -> hcatN, all in LDS ====
#define UPSTR 72                 // ch-stride of upB in shorts (16B-aligned)
#define UPROW (34 * UPSTR)       // shorts per upB row (34 lpx)
__global__ __launch_bounds__(256) void front_kernel(
    const float* __restrict__ x1, const short* __restrict__ Wbk,
    const float* __restrict__ bk, const float* __restrict__ Wq,
    const float* __restrict__ bq, const float* __restrict__ x2,
    const float* __restrict__ Wv, const float* __restrict__ bv,
    short* __restrict__ hcatN)
{
    __shared__ __align__(16) short upB[3 * UPROW];   // [r][lpx 0..33][ch 0..63]
    __shared__ float kfs[16 * 33];                   // [k][px 0..31], stride 33
    __shared__ float qbuf[32 * 65];                  // [px][ch], stride 65
    __shared__ int tr[32 * 33];                      // [chpair][px], stride 33
    int bid = blockIdx.x;
    const int xq = bid & 3;
    const int y = (bid >> 2) & 127;
    const int b = bid >> 9;
    const int t = threadIdx.x;
    const int X0 = xq * 32;

    // ---- phase 1: upsample rows y-1..y+1 (bf16) into upB, zeros outside ----
    {
        const int px1 = t & 31, cg1 = t >> 5;        // 32 px x 8 ch-groups
        const int gx = X0 + px1;
        float fx = (float)(gx * 63) / 127.f;
        int x0 = (int)fx; float wx = fx - (float)x0; int x1i = min(x0 + 1, 63);
        #pragma unroll
        for (int r = 0; r < 3; r++) {
            int ry = y + r - 1;
            bool rv = ((unsigned)ry < 128u);
            int ryc = rv ? ry : 0;
            float fy = (float)(ryc * 63) / 127.f;
            int y0 = (int)fy; float wy = fy - (float)y0; int y1 = min(y0 + 1, 63);
            int pk[4];
            #pragma unroll
            for (int jj = 0; jj < 4; jj++) {
                unsigned lohi[2];
                #pragma unroll
                for (int h = 0; h < 2; h++) {
                    int ch = cg1 * 8 + jj * 2 + h;
                    float v = 0.f;
                    if (rv) {
                        const float* sp = x1 + ((size_t)(b * 64 + ch) << 12);
                        float v00 = sp[(y0 << 6) + x0], v01 = sp[(y0 << 6) + x1i];
                        float v10 = sp[(y1 << 6) + x0], v11 = sp[(y1 << 6) + x1i];
                        float top = v00 * (1.f - wx) + v01 * wx;
                        float bot = v10 * (1.f - wx) + v11 * wx;
                        v = top * (1.f - wy) + bot * wy;
                    }
                    lohi[h] = (unsigned)(unsigned short)bf16rne(v);
                }
                pk[jj] = (int)(lohi[0] | (lohi[1] << 16));
            }
            *(int4*)(upB + r * UPROW + (px1 + 1) * UPSTR + cg1 * 8) =
                make_int4(pk[0], pk[1], pk[2], pk[3]);
        }
        if (t < 48) {                                // halo: r x side x cg
            int r = t >> 4, side = (t >> 3) & 1, cg = t & 7;
            int gxh = X0 + (side ? 32 : -1);
            int lpx = side ? 33 : 0;
            int ry = y + r - 1;
            bool v_ok = ((unsigned)ry < 128u) && ((unsigned)gxh < 128u);
            int ryc = ((unsigned)ry < 128u) ? ry : 0;
            float fy = (float)(ryc * 63) / 127.f;
            int y0 = (int)fy; float wy = fy - (float)y0; int y1 = min(y0 + 1, 63);
            int gxc = min(max(gxh, 0), 127);
            float fxh = (float)(gxc * 63) / 127.f;
            int hx0 = (int)fxh; float hwx = fxh - (float)hx0; int hx1 = min(hx0 + 1, 63);
            int pk[4];
            #pragma unroll
            for (int jj = 0; jj < 4; jj++) {
                unsigned lohi[2];
                #pragma unroll
                for (int h = 0; h < 2; h++) {
                    int ch = cg * 8 + jj * 2 + h;
                    float v = 0.f;
                    if (v_ok) {
                        const float* sp = x1 + ((size_t)(b * 64 + ch) << 12);
                        float v00 = sp[(y0 << 6) + hx0], v01 = sp[(y0 << 6) + hx1];
                        float v10 = sp[(y1 << 6) + hx0], v11 = sp[(y1 << 6) + hx1];
                        float top = v00 * (1.f - hwx) + v01 * hwx;
                        float bot = v10 * (1.f - hwx) + v11 * hwx;
                        v = top * (1.f - wy) + bot * wy;
                    }
                    lohi[h] = (unsigned)(unsigned short)bf16rne(v);
                }
                pk[jj] = (int)(lohi[0] | (lohi[1] << 16));
            }
            *(int4*)(upB + r * UPROW + lpx * UPSTR + cg * 8) =
                make_int4(pk[0], pk[1], pk[2], pk[3]);
        }
    }
    __syncthreads();

    // ---- phase 2: waves 0-1: Kf MFMA (16 px each); waves 2-3: qconv --------
    {
        const int w = t >> 6, l = t & 63;
        if (w < 2) {
            const int lx = l & 15, kg = l >> 4;
            const short* wbase = Wbk + (size_t)l * 8;
            f32x4 acc = (f32x4)(0.f);
            #pragma unroll
            for (int ty = 0; ty < 3; ty++) {
                #pragma unroll
                for (int tx = 0; tx < 3; tx++) {
                    const short* ab = upB + ty * UPROW + (size_t)(w * 16 + lx + tx) * UPSTR;
                    #pragma unroll
                    for (int ch = 0; ch < 2; ch++) {
                        short8v a = *(const short8v*)(ab + kg * 8 + ch * 32);
                        short8v bf = *(const short8v*)(wbase +
                            (size_t)((ty * 3 + tx) * 2 + ch) * 512);
                        acc = __builtin_amdgcn_mfma_f32_16x16x32_bf16(a, bf, acc, 0, 0, 0);
                    }
                }
            }
            float bb = bk[lx];
            #pragma unroll
            for (int r = 0; r < 4; r++)
                kfs[lx * 33 + (w * 16 + kg * 4 + r)] = fmaxf(acc[r] + bb, 0.f);
        } else {
            // depthwise qconv, ch-major sliding window (conflict-free LDS reads)
            const int ch = l;
            const int px0 = (w - 2) * 16;
            const float* wqp = Wq + ch * 9;
            float wq[9];
            #pragma unroll
            for (int i = 0; i < 9; i++) wq[i] = wqp[i];
            float bqc = bq[ch];
            float a0[3], a1[3];
            #pragma unroll
            for (int r = 0; r < 3; r++) {
                a0[r] = bf16tof(upB[r * UPROW + px0 * UPSTR + ch]);
                a1[r] = bf16tof(upB[r * UPROW + (px0 + 1) * UPSTR + ch]);
            }
            for (int p = 0; p < 16; p++) {
                float a2[3];
                #pragma unroll
                for (int r = 0; r < 3; r++)
                    a2[r] = bf16tof(upB[r * UPROW + (px0 + p + 2) * UPSTR + ch]);
                float q = bqc;
                #pragma unroll
                for (int r = 0; r < 3; r++)
                    q = fmaf(a0[r], wq[r * 3 + 0],
                        fmaf(a1[r], wq[r * 3 + 1], fmaf(a2[r], wq[r * 3 + 2], q)));
                qbuf[(px0 + p) * 65 + ch] = fmaxf(q, 0.f);
                #pragma unroll
                for (int r = 0; r < 3; r++) { a0[r] = a1[r]; a1[r] = a2[r]; }
            }
        }
    }
    __syncthreads();

    // ---- phase 3: softmax gate, 32 px x 64 ch -------------------------------
    {
        const int px = t & 31, cg = t >> 5;
        const int x = X0 + px;
        float kv[16];
        #pragma unroll
        for (int k = 0; k < 16; k++) kv[k] = kfs[k * 33 + px];
        float kvmax = kv[0];
        #pragma unroll
        for (int k = 1; k < 16; k++) kvmax = fmaxf(kvmax, kv[k]);
        float wvv[16], bvv[16];
        #pragma unroll
        for (int k = 0; k < 16; k++) { wvv[k] = Wv[k]; bvv[k] = bv[k]; }
        float xvv[8], qv[8];
        #pragma unroll
        for (int j = 0; j < 8; j++) {
            xvv[j] = x2[((size_t)(b * 64 + cg * 8 + j) << 14) + (y << 7) + x];
            qv[j] = qbuf[px * 65 + cg * 8 + j];
        }
        #pragma unroll
        for (int jj = 0; jj < 4; jj++) {
            int gpk = 0;
            #pragma unroll
            for (int h = 0; h < 2; h++) {
                const int j = jj * 2 + h;
                float q = qv[j];
                float mx = q * kvmax;                // q,kv >= 0 => exact max
                float den = 0.f, num = 0.f;
                #pragma unroll
                for (int k = 0; k < 16; k++) {
                    float e = __expf(fmaf(q, kv[k], -mx));
                    den += e;
                    float V = fmaxf(fmaf(xvv[j], wvv[k], bvv[k]), 0.f);
                    num = fmaf(e, V, num);
                }
                unsigned u = (unsigned)(unsigned short)bf16rne(num / den);
                gpk |= (int)(u << (h * 16));
            }
            tr[(cg * 4 + jj) * 33 + px] = gpk;
        }
    }
    __syncthreads();

    // ---- phase 4: coalesced writes: gate -> ch 0..63, upB row1 -> ch 64..127
    {
        const int px4 = t >> 3, cq = t & 7;
        int pp = (y + 1) * 130 + X0 + px4 + 1;
        int wd[4];
        #pragma unroll
        for (int i = 0; i < 4; i++) wd[i] = tr[(cq * 4 + i) * 33 + px4];
        int* dpL = (int*)hcatN + ((size_t)b * PADPIX + pp) * 64 + cq * 4;
        *(int4*)dpL = make_int4(wd[0], wd[1], wd[2], wd[3]);
        const short* us = upB + UPROW + (size_t)(px4 + 1) * UPSTR + cq * 8;
        int4 u = *(const int4*)us;
        int* dpU = (int*)hcatN + ((size_t)b * PADPIX + pp) * 64 + 32 + cq * 4;
        *(int4*)dpU = u;
    }
}

// ===== MFMA implicit-GEMM 3x3 conv, LDS-staged A-slab + race-free stats ======
// Block = 32 px of one row x all COUT. A-slab (3 rows x 34 px x CIN) staged in
// LDS with one coalesced pass + single barrier; K-loop A = conflict-free
// ds_read_b128 (stride LDSTR verified 8 words/bank), B = contiguous L2 reads.
template<int PSTR, int LDSTR, int CIN, int COUT, int NWN, int OPW>
__global__ __launch_bounds__(256) void convmfma_kernel(
    const short* __restrict__ actN, const short* __restrict__ Wb,
    float* __restrict__ dst, float* __restrict__ partials)
{
    constexpr int NCH = CIN / 32, NOCT = COUT / 16, NWM = 4 / NWN;
    constexpr int EXT = NWM * 16;
    constexpr int SEG = 128 / EXT;
    __shared__ __align__(16) short slab[3 * 34 * LDSTR];
    const int t = threadIdx.x;
    const int w = t >> 6, l = t & 63;
    const int wn = w % NWN, wm = w / NWN;
    int bid = blockIdx.x;
    const int xseg = bid % SEG; bid /= SEG;
    const int y = bid & 127;
    const int b = bid >> 7;
    const int lx = l & 15, kg = l >> 4;
    const int X0 = xseg * EXT;

    // ---- stage 3 rows x 34 px x CIN into LDS (all in-bounds of padded buf) --
    constexpr int ROWI4 = 34 * PSTR / 8;             // int4 per slab row
    constexpr int PXI4 = PSTR / 8;                   // int4 per pixel (pow2)
    #pragma unroll
    for (int r = 0; r < 3; r++) {
        const int4* src = (const int4*)(actN +
            ((size_t)b * PADPIX + (size_t)(y + r) * 130 + X0) * PSTR);
        for (int i = t; i < ROWI4; i += 256) {
            int p = i / PXI4, cq = i % PXI4;
            *(int4*)(slab + (r * 34 + p) * LDSTR + cq * 8) = src[i];
        }
    }
    __syncthreads();

    const short* wbase = Wb + (size_t)(wn * OPW) * 512 + (size_t)l * 8;

    f32x4 acc[OPW];
    #pragma unroll
    for (int p = 0; p < OPW; p++) acc[p] = (f32x4)(0.f);

    #pragma unroll
    for (int ty = 0; ty < 3; ty++) {
        #pragma unroll
        for (int tx = 0; tx < 3; tx++) {
            const short* ab = slab + (ty * 34 + wm * 16 + lx + tx) * LDSTR + kg * 8;
            const int tap = ty * 3 + tx;
            #pragma unroll
            for (int ch = 0; ch < NCH; ch++) {
                short8v a = *(const short8v*)(ab + ch * 32);
                #pragma unroll
                for (int p = 0; p < OPW; p++) {
                    short8v bf = *(const short8v*)(wbase +
                        (size_t)((tap * NCH + ch) * NOCT + p) * 512);
                    acc[p] = __builtin_amdgcn_mfma_f32_16x16x32_bf16(a, bf, acc[p], 0, 0, 0);
                }
            }
        }
    }

    const int ox = X0 + wm * 16 + kg * 4;
    #pragma unroll
    for (int p = 0; p < OPW; p++) {
        const int oc = (wn * OPW + p) * 16 + lx;
        *(f32x4*)(dst + (((size_t)(b * COUT + oc)) << 14) + (y << 7) + ox) = acc[p];
    }

    // per-wave BN partials: shfl reduce over the 4 kg groups, plain stores
    #pragma unroll
    for (int p = 0; p < OPW; p++) {
        float s = 0.f, q2 = 0.f;
        f32x4 v = acc[p];
        #pragma unroll
        for (int r = 0; r < 4; r++) { s += v[r]; q2 = fmaf(v[r], v[r], q2); }
        s += __shfl_xor(s, 16); q2 += __shfl_xor(q2, 16);
        s += __shfl_xor(s, 32); q2 += __shfl_xor(q2, 32);
        if (l < 16) {
            const int oc = (wn * OPW + p) * 16 + lx;
            float* dp = partials + (((size_t)blockIdx.x * NWM + wm) * 64 + oc) * 2;
            dp[0] = s;
            dp[1] = q2;
        }
    }
}

// ===== reduce 2048 partial pairs per channel -> raw sums (no atomics) ========
__global__ void bnred_kernel(const float* __restrict__ partials,
                             float* __restrict__ statsAcc) {
    int ch = blockIdx.x;                                 // 64 blocks
    const int t = threadIdx.x;
    float s = 0.f, q = 0.f;
    for (int i = t; i < 2048; i += 256) {
        const float* p = partials + ((size_t)i * 64 + ch) * 2;
        s += p[0];
        q += p[1];
    }
    __shared__ float sh[512];
    sh[t] = s;
    sh[256 + t] = q;
    __syncthreads();
    for (int off = 128; off > 0; off >>= 1) {
        if (t < off) {
            sh[t] += sh[t + off];
            sh[256 + t] += sh[256 + t + off];
        }
        __syncthreads();
    }
    if (t == 0) {
        statsAcc[ch * 2] = sh[0];
        statsAcc[ch * 2 + 1] = sh[256];
    }
}

// ===== NCHW fp32 -> padded NHWC bf16 with inline-finalized BN + relu =========
__global__ __launch_bounds__(256) void packN_kernel(
    const float* __restrict__ src, const float* __restrict__ statsAcc,
    const float* __restrict__ g, const float* __restrict__ beta,
    short* __restrict__ h1N)
{
    __shared__ int lds[32 * 65];
    int bid = blockIdx.x;
    const int pxt = bid & 255;
    const int b = bid >> 8;
    const int t = threadIdx.x;
    {
        const int cw = t >> 3, pg = t & 7;
        #pragma unroll
        for (int h = 0; h < 2; h++) {
            int c = cw * 2 + h;
            float mean = statsAcc[c * 2] * (1.f / 32768.f);
            float var  = statsAcc[c * 2 + 1] * (1.f / 32768.f) - mean * mean;
            float sc = g[c] * rsqrtf(var + 1e-5f);
            float sh = beta[c] - mean * sc;
            const float* sp = src + ((size_t)(b * 64 + c) << 14) + pxt * 64 + pg * 8;
            float4 v0 = *(const float4*)sp;
            float4 v1 = *(const float4*)(sp + 4);
            float vals[8] = {v0.x, v0.y, v0.z, v0.w, v1.x, v1.y, v1.z, v1.w};
            #pragma unroll
            for (int i = 0; i < 8; i++) {
                float v = fmaxf(fmaf(vals[i], sc, sh), 0.f);
                unsigned wv = (unsigned)(unsigned short)bf16rne(v);
                if (h == 0) lds[cw * 65 + pg * 8 + i] = (int)wv;
                else        lds[cw * 65 + pg * 8 + i] |= (int)(wv << 16);
            }
        }
    }
    __syncthreads();
    {
        const int px = t >> 2, cq = t & 3;
        int wd[8];
        #pragma unroll
        for (int i = 0; i < 8; i++) wd[i] = lds[(cq * 8 + i) * 65 + px];
        int pixel = pxt * 64 + px;
        int yy = pixel >> 7, xx = pixel & 127;
        int pp = (yy + 1) * 130 + xx + 1;
        int* dp = (int*)h1N + ((size_t)b * PADPIX + pp) * 32 + cq * 8;
        *(int4*)dp = make_int4(wd[0], wd[1], wd[2], wd[3]);
        *(int4*)(dp + 4) = make_int4(wd[4], wd[5], wd[6], wd[7]);
    }
}

// ===== inline-finalized BN + relu + split o1/o2 -> d_out =====================
__global__ void norm2_kernel(const float4* __restrict__ src,
                             const float* __restrict__ statsAcc,
                             const float* __restrict__ g, const float* __restrict__ beta,
                             float4* __restrict__ out) {
    int idx4 = blockIdx.x * 256 + threadIdx.x;           // over 2*64*4096
    int q = idx4 & 4095;
    int c = (idx4 >> 12) & 63;
    int b = idx4 >> 18;
    float mean = statsAcc[c * 2] * (1.f / 32768.f);
    float var  = statsAcc[c * 2 + 1] * (1.f / 32768.f) - mean * mean;
    float sc = g[c] * rsqrtf(var + 1e-5f);
    float sh = beta[c] - mean * sc;
    float4 v = src[idx4];
    v.x = fmaxf(fmaf(v.x, sc, sh), 0.f);
    v.y = fmaxf(fmaf(v.y, sc, sh), 0.f);
    v.z = fmaxf(fmaf(v.z, sc, sh), 0.f);
    v.w = fmaxf(fmaf(v.w, sc, sh), 0.f);
    int half = c >> 5, cc = c & 31;
    out[(size_t)half * 262144 + (((size_t)(b * 32 + cc)) << 12) + q] = v;
}

extern "C" void kernel_launch(void* const* d_in, const int* in_sizes, int n_in,
                              void* d_out, int out_size, void* d_ws, size_t ws_size,
                              hipStream_t stream) {
    const float* x1 = (const float*)d_in[0];
    // d_in[1] (x1_) is unused by the reference
    const float* x2 = (const float*)d_in[2];
    const float* Wq = (const float*)d_in[3];
    const float* bq = (const float*)d_in[4];
    const float* Wk = (const float*)d_in[5];
    const float* bk = (const float*)d_in[6];
    const float* Wv = (const float*)d_in[7];
    const float* bv = (const float*)d_in[8];
    const float* W1 = (const float*)d_in[9];
    const float* g1 = (const float*)d_in[10];
    const float* b1 = (const float*)d_in[11];
    const float* W2 = (const float*)d_in[12];
    const float* g2 = (const float*)d_in[13];
    const float* b2 = (const float*)d_in[14];
    float* out = (float*)d_out;
    float* ws = (float*)d_ws;

    // workspace layout (float offsets)
    float* c1out    = ws;                        // [2][64][HW] fp32     (2,097,152)
    float* stacc    = ws + 2097152;              // 256 raw sums (s1 @ +0, s2 @ +128)
    short* hcatN    = (short*)(ws + 2097408);    // [2][PADPIX][128] bf16 (2,163,200 f)
    short* h1N      = (short*)(ws + 4260608);    // [2][PADPIX][64]  bf16 (1,081,600 f)
    short* Wb1      = (short*)(ws + 5342208);    // 73728 shorts = 36864 f
    short* Wb2      = (short*)(ws + 5379072);    // 36864 shorts = 18432 f
    short* Wbk      = (short*)(ws + 5397504);    // 9216 shorts  =  4608 f
    float* partials = ws + 5402112;              // 1024*2*64*2 = 262,144 f (1 MB)

    // K1: weight prep + border zeroing + stats zero
    k1_kernel<<<566, 256, 0, stream>>>(W1, W2, Wk, Wb1, Wb2, Wbk, hcatN, h1N, stacc);

    // front: upsample + Kf conv + qconv + gate, fused -> hcatN (both halves)
    front_kernel<<<1024, 256, 0, stream>>>(x1, Wbk, bk, Wq, bq, x2, Wv, bv, hcatN);

    // conv1 128->64, LDS-staged A (LDSTR=136: 16B-aligned, 8 words/bank)
    convmfma_kernel<128, 136, 128, 64, 2, 2><<<1024, 256, 0, stream>>>(
        hcatN, Wb1, c1out, partials);
    bnred_kernel<<<64, 256, 0, stream>>>(partials, stacc);
    packN_kernel<<<512, 256, 0, stream>>>(c1out, stacc, g1, b1, h1N);

    // conv2 64->64, LDS-staged A (LDSTR=72)
    convmfma_kernel<64, 72, 64, 64, 2, 2><<<1024, 256, 0, stream>>>(
        h1N, Wb2, c1out, partials);
    bnred_kernel<<<64, 256, 0, stream>>>(partials, stacc + 128);
    norm2_kernel<<<2048, 256, 0, stream>>>((const float4*)c1out, stacc + 128, g2, b2,
                                           (float4*)out);
}

// Round 19
// 70.121 us; speedup vs baseline: 12.7358x; 1.0797x over previous
//
#include <hip/hip_runtime.h>

#define HW 16384        // 128*128
#define PADPIX 16900    // 130*130 padded pixel count

typedef __attribute__((ext_vector_type(8))) short short8v;
typedef __attribute__((ext_vector_type(4))) float f32x4;

__device__ inline short bf16rne(float x) {
    unsigned u = __float_as_uint(x);
    unsigned r = (u + 0x7fffu + ((u >> 16) & 1u)) >> 16;
    return (short)r;
}
__device__ inline float bf16tof(short s) {
    return __uint_as_float(((unsigned)(unsigned short)s) << 16);
}

// padded-pixel index for border element j (j in 0..515)
__device__ inline int border_pp(int j) {
    if (j < 130) return j;                          // row 0
    if (j < 260) return 129 * 130 + (j - 130);      // row 129
    if (j < 388) return (j - 259) * 130;            // col 0, rows 1..128
    return (j - 387) * 130 + 129;                   // col 129, rows 1..128
}

// ===== K1: weight prep (0..467) + borders (468..564) =========================
__global__ __launch_bounds__(256) void k1_kernel(
    const float* __restrict__ W1, const float* __restrict__ W2,
    const float* __restrict__ Wk,
    short* __restrict__ Wb1, short* __restrict__ Wb2, short* __restrict__ Wbk,
    short* __restrict__ hcatN, short* __restrict__ h1N)
{
    int bid = blockIdx.x;
    const int t = threadIdx.x;
    if (bid < 468) {
        const float* W; short* Wb; int CIN, COUT, idx;
        if (bid < 288)      { W = W1; Wb = Wb1; CIN = 128; COUT = 64; idx = bid * 256 + t; }
        else if (bid < 432) { W = W2; Wb = Wb2; CIN = 64;  COUT = 64; idx = (bid - 288) * 256 + t; }
        else                { W = Wk; Wb = Wbk; CIN = 64;  COUT = 16; idx = (bid - 432) * 256 + t; }
        int NOCT = COUT >> 4, NCH = CIN >> 5;
        int total = 9 * NCH * NOCT * 512;
        if (idx >= total) return;
        int j = idx & 7, l = (idx >> 3) & 63;
        int rest = idx >> 9;
        int oct = rest % NOCT; rest /= NOCT;
        int ch = rest % NCH;
        int tap = rest / NCH;
        int o = oct * 16 + (l & 15);
        int c = ch * 32 + (l >> 4) * 8 + j;
        Wb[idx] = bf16rne(W[((size_t)o * CIN + c) * 9 + tap]);
        return;
    }
    // ---- zero borders of hcatN (16512 int4) and h1N (8256 int4) ----
    int t2 = (bid - 468) * 256 + t;
    const int4 z = make_int4(0, 0, 0, 0);
    if (t2 < 16512) {
        int px = t2 >> 4, q = t2 & 15;
        int b = px >= 516; int j = px - b * 516;
        int pp = border_pp(j);
        ((int4*)hcatN)[((size_t)b * PADPIX + pp) * 16 + q] = z;
    } else if (t2 < 24768) {
        int idx = t2 - 16512;
        int px = idx >> 3, q = idx & 7;
        int b = px >= 516; int j = px - b * 516;
        int pp = border_pp(j);
        ((int4*)h1N)[((size_t)b * PADPIX + pp) * 8 + q] = z;
    }
}

// ===== front: upsample -> (Kf MFMA || qconv) -> gate -> hcatN, all in LDS ====
#define UPSTR 72                 // ch-stride of upB in shorts (16B-aligned)
#define UPROW (34 * UPSTR)       // shorts per upB row (34 lpx)
__global__ __launch_bounds__(256) void front_kernel(
    const float* __restrict__ x1, const short* __restrict__ Wbk,
    const float* __restrict__ bk, const float* __restrict__ Wq,
    const float* __restrict__ bq, const float* __restrict__ x2,
    const float* __restrict__ Wv, const float* __restrict__ bv,
    short* __restrict__ hcatN)
{
    __shared__ __align__(16) short upB[3 * UPROW];   // [r][lpx 0..33][ch 0..63]
    __shared__ float kfs[16 * 33];                   // [k][px 0..31], stride 33
    __shared__ float qbuf[32 * 65];                  // [px][ch], stride 65
    __shared__ int tr[32 * 33];                      // [chpair][px], stride 33
    int bid = blockIdx.x;
    const int xq = bid & 3;
    const int y = (bid >> 2) & 127;
    const int b = bid >> 9;
    const int t = threadIdx.x;
    const int X0 = xq * 32;

    // ---- phase 1: upsample rows y-1..y+1 (bf16) into upB, zeros outside ----
    {
        const int px1 = t & 31, cg1 = t >> 5;        // 32 px x 8 ch-groups
        const int gx = X0 + px1;
        float fx = (float)(gx * 63) / 127.f;
        int x0 = (int)fx; float wx = fx - (float)x0; int x1i = min(x0 + 1, 63);
        #pragma unroll
        for (int r = 0; r < 3; r++) {
            int ry = y + r - 1;
            bool rv = ((unsigned)ry < 128u);
            int ryc = rv ? ry : 0;
            float fy = (float)(ryc * 63) / 127.f;
            int y0 = (int)fy; float wy = fy - (float)y0; int y1 = min(y0 + 1, 63);
            int pk[4];
            #pragma unroll
            for (int jj = 0; jj < 4; jj++) {
                unsigned lohi[2];
                #pragma unroll
                for (int h = 0; h < 2; h++) {
                    int ch = cg1 * 8 + jj * 2 + h;
                    float v = 0.f;
                    if (rv) {
                        const float* sp = x1 + ((size_t)(b * 64 + ch) << 12);
                        float v00 = sp[(y0 << 6) + x0], v01 = sp[(y0 << 6) + x1i];
                        float v10 = sp[(y1 << 6) + x0], v11 = sp[(y1 << 6) + x1i];
                        float top = v00 * (1.f - wx) + v01 * wx;
                        float bot = v10 * (1.f - wx) + v11 * wx;
                        v = top * (1.f - wy) + bot * wy;
                    }
                    lohi[h] = (unsigned)(unsigned short)bf16rne(v);
                }
                pk[jj] = (int)(lohi[0] | (lohi[1] << 16));
            }
            *(int4*)(upB + r * UPROW + (px1 + 1) * UPSTR + cg1 * 8) =
                make_int4(pk[0], pk[1], pk[2], pk[3]);
        }
        if (t < 48) {                                // halo: r x side x cg
            int r = t >> 4, side = (t >> 3) & 1, cg = t & 7;
            int gxh = X0 + (side ? 32 : -1);
            int lpx = side ? 33 : 0;
            int ry = y + r - 1;
            bool v_ok = ((unsigned)ry < 128u) && ((unsigned)gxh < 128u);
            int ryc = ((unsigned)ry < 128u) ? ry : 0;
            float fy = (float)(ryc * 63) / 127.f;
            int y0 = (int)fy; float wy = fy - (float)y0; int y1 = min(y0 + 1, 63);
            int gxc = min(max(gxh, 0), 127);
            float fxh = (float)(gxc * 63) / 127.f;
            int hx0 = (int)fxh; float hwx = fxh - (float)hx0; int hx1 = min(hx0 + 1, 63);
            int pk[4];
            #pragma unroll
            for (int jj = 0; jj < 4; jj++) {
                unsigned lohi[2];
                #pragma unroll
                for (int h = 0; h < 2; h++) {
                    int ch = cg * 8 + jj * 2 + h;
                    float v = 0.f;
                    if (v_ok) {
                        const float* sp = x1 + ((size_t)(b * 64 + ch) << 12);
                        float v00 = sp[(y0 << 6) + hx0], v01 = sp[(y0 << 6) + hx1];
                        float v10 = sp[(y1 << 6) + hx0], v11 = sp[(y1 << 6) + hx1];
                        float top = v00 * (1.f - hwx) + v01 * hwx;
                        float bot = v10 * (1.f - hwx) + v11 * hwx;
                        v = top * (1.f - wy) + bot * wy;
                    }
                    lohi[h] = (unsigned)(unsigned short)bf16rne(v);
                }
                pk[jj] = (int)(lohi[0] | (lohi[1] << 16));
            }
            *(int4*)(upB + r * UPROW + lpx * UPSTR + cg * 8) =
                make_int4(pk[0], pk[1], pk[2], pk[3]);
        }
    }
    __syncthreads();

    // ---- phase 2: waves 0-1: Kf MFMA (16 px each); waves 2-3: qconv --------
    {
        const int w = t >> 6, l = t & 63;
        if (w < 2) {
            const int lx = l & 15, kg = l >> 4;
            const short* wbase = Wbk + (size_t)l * 8;
            f32x4 acc = (f32x4)(0.f);
            #pragma unroll
            for (int ty = 0; ty < 3; ty++) {
                #pragma unroll
                for (int tx = 0; tx < 3; tx++) {
                    const short* ab = upB + ty * UPROW + (size_t)(w * 16 + lx + tx) * UPSTR;
                    #pragma unroll
                    for (int ch = 0; ch < 2; ch++) {
                        short8v a = *(const short8v*)(ab + kg * 8 + ch * 32);
                        short8v bf = *(const short8v*)(wbase +
                            (size_t)((ty * 3 + tx) * 2 + ch) * 512);
                        acc = __builtin_amdgcn_mfma_f32_16x16x32_bf16(a, bf, acc, 0, 0, 0);
                    }
                }
            }
            float bb = bk[lx];
            #pragma unroll
            for (int r = 0; r < 4; r++)
                kfs[lx * 33 + (w * 16 + kg * 4 + r)] = fmaxf(acc[r] + bb, 0.f);
        } else {
            // depthwise qconv, ch-major sliding window (conflict-free LDS reads)
            const int ch = l;
            const int px0 = (w - 2) * 16;
            const float* wqp = Wq + ch * 9;
            float wq[9];
            #pragma unroll
            for (int i = 0; i < 9; i++) wq[i] = wqp[i];
            float bqc = bq[ch];
            float a0[3], a1[3];
            #pragma unroll
            for (int r = 0; r < 3; r++) {
                a0[r] = bf16tof(upB[r * UPROW + px0 * UPSTR + ch]);
                a1[r] = bf16tof(upB[r * UPROW + (px0 + 1) * UPSTR + ch]);
            }
            for (int p = 0; p < 16; p++) {
                float a2[3];
                #pragma unroll
                for (int r = 0; r < 3; r++)
                    a2[r] = bf16tof(upB[r * UPROW + (px0 + p + 2) * UPSTR + ch]);
                float q = bqc;
                #pragma unroll
                for (int r = 0; r < 3; r++)
                    q = fmaf(a0[r], wq[r * 3 + 0],
                        fmaf(a1[r], wq[r * 3 + 1], fmaf(a2[r], wq[r * 3 + 2], q)));
                qbuf[(px0 + p) * 65 + ch] = fmaxf(q, 0.f);
                #pragma unroll
                for (int r = 0; r < 3; r++) { a0[r] = a1[r]; a1[r] = a2[r]; }
            }
        }
    }
    __syncthreads();

    // ---- phase 3: softmax gate, 32 px x 64 ch -------------------------------
    {
        const int px = t & 31, cg = t >> 5;
        const int x = X0 + px;
        float kv[16];
        #pragma unroll
        for (int k = 0; k < 16; k++) kv[k] = kfs[k * 33 + px];
        float kvmax = kv[0];
        #pragma unroll
        for (int k = 1; k < 16; k++) kvmax = fmaxf(kvmax, kv[k]);
        float wvv[16], bvv[16];
        #pragma unroll
        for (int k = 0; k < 16; k++) { wvv[k] = Wv[k]; bvv[k] = bv[k]; }
        float xvv[8], qv[8];
        #pragma unroll
        for (int j = 0; j < 8; j++) {
            xvv[j] = x2[((size_t)(b * 64 + cg * 8 + j) << 14) + (y << 7) + x];
            qv[j] = qbuf[px * 65 + cg * 8 + j];
        }
        #pragma unroll
        for (int jj = 0; jj < 4; jj++) {
            int gpk = 0;
            #pragma unroll
            for (int h = 0; h < 2; h++) {
                const int j = jj * 2 + h;
                float q = qv[j];
                float mx = q * kvmax;                // q,kv >= 0 => exact max
                float den = 0.f, num = 0.f;
                #pragma unroll
                for (int k = 0; k < 16; k++) {
                    float e = __expf(fmaf(q, kv[k], -mx));
                    den += e;
                    float V = fmaxf(fmaf(xvv[j], wvv[k], bvv[k]), 0.f);
                    num = fmaf(e, V, num);
                }
                unsigned u = (unsigned)(unsigned short)bf16rne(num / den);
                gpk |= (int)(u << (h * 16));
            }
            tr[(cg * 4 + jj) * 33 + px] = gpk;
        }
    }
    __syncthreads();

    // ---- phase 4: coalesced writes: gate -> ch 0..63, upB row1 -> ch 64..127
    {
        const int px4 = t >> 3, cq = t & 7;
        int pp = (y + 1) * 130 + X0 + px4 + 1;
        int wd[4];
        #pragma unroll
        for (int i = 0; i < 4; i++) wd[i] = tr[(cq * 4 + i) * 33 + px4];
        int* dpL = (int*)hcatN + ((size_t)b * PADPIX + pp) * 64 + cq * 4;
        *(int4*)dpL = make_int4(wd[0], wd[1], wd[2], wd[3]);
        const short* us = upB + UPROW + (size_t)(px4 + 1) * UPSTR + cq * 8;
        int4 u = *(const int4*)us;
        int* dpU = (int*)hcatN + ((size_t)b * PADPIX + pp) * 64 + 32 + cq * 4;
        *(int4*)dpU = u;
    }
}

// ===== MFMA implicit-GEMM 3x3 conv, LDS-staged A-slab ========================
// OUTBF16: write raw (unnormalized) bf16 to padded NHWC dstB.
// INBN: apply BN(scale,shift)+relu inline while staging (borders forced to 0).
template<int PSTR, int LDSTR, int CIN, int COUT, int NWN, int OPW,
         bool OUTBF16, bool INBN>
__global__ __launch_bounds__(256) void convmfma_kernel(
    const short* __restrict__ actN, const short* __restrict__ Wb,
    float* __restrict__ dstF, short* __restrict__ dstB,
    const float* __restrict__ statsAcc,
    const float* __restrict__ g, const float* __restrict__ beta,
    float* __restrict__ partials)
{
    constexpr int NCH = CIN / 32, NOCT = COUT / 16, NWM = 4 / NWN;
    constexpr int EXT = NWM * 16;
    constexpr int SEG = 128 / EXT;
    __shared__ __align__(16) short slab[3 * 34 * LDSTR];
    __shared__ float scsh[INBN ? 128 : 2];
    const int t = threadIdx.x;
    const int w = t >> 6, l = t & 63;
    const int wn = w % NWN, wm = w / NWN;
    int bid = blockIdx.x;
    const int xseg = bid % SEG; bid /= SEG;
    const int y = bid & 127;
    const int b = bid >> 7;
    const int lx = l & 15, kg = l >> 4;
    const int X0 = xseg * EXT;

    if (INBN) {
        if (t < 64) {
            float mean = statsAcc[t * 2] * (1.f / 32768.f);
            float var  = statsAcc[t * 2 + 1] * (1.f / 32768.f) - mean * mean;
            float sc = g[t] * rsqrtf(var + 1e-5f);
            scsh[t] = sc;
            scsh[64 + t] = beta[t] - mean * sc;
        }
        __syncthreads();
    }

    // ---- stage 3 rows x 34 px x CIN into LDS (all in-bounds of padded buf) --
    constexpr int ROWI4 = 34 * PSTR / 8;             // int4 per slab row
    constexpr int PXI4 = PSTR / 8;                   // int4 per pixel (pow2)
    #pragma unroll
    for (int r = 0; r < 3; r++) {
        const int prow = y + r;                      // padded row 0..129
        const bool rowb = (prow == 0) || (prow == 129);
        const int4* src = (const int4*)(actN +
            ((size_t)b * PADPIX + (size_t)prow * 130 + X0) * PSTR);
        for (int i = t; i < ROWI4; i += 256) {
            int p = i / PXI4, cq = i % PXI4;
            int4 v = src[i];
            if (INBN) {
                int pcol = X0 + p;                   // padded col 0..129
                if (rowb || pcol == 0 || pcol == 129) {
                    v = make_int4(0, 0, 0, 0);
                } else {
                    int ch0 = cq * 8;
                    int* vw = (int*)&v;
                    #pragma unroll
                    for (int wd = 0; wd < 4; wd++) {
                        int c0 = ch0 + wd * 2, c1 = c0 + 1;
                        float lo = bf16tof((short)(vw[wd] & 0xFFFF));
                        float hi = bf16tof((short)((unsigned)vw[wd] >> 16));
                        lo = fmaxf(fmaf(lo, scsh[c0], scsh[64 + c0]), 0.f);
                        hi = fmaxf(fmaf(hi, scsh[c1], scsh[64 + c1]), 0.f);
                        unsigned ulo = (unsigned)(unsigned short)bf16rne(lo);
                        unsigned uhi = (unsigned)(unsigned short)bf16rne(hi);
                        vw[wd] = (int)(ulo | (uhi << 16));
                    }
                }
            }
            *(int4*)(slab + (r * 34 + p) * LDSTR + cq * 8) = v;
        }
    }
    __syncthreads();

    const short* wbase = Wb + (size_t)(wn * OPW) * 512 + (size_t)l * 8;

    f32x4 acc[OPW];
    #pragma unroll
    for (int p = 0; p < OPW; p++) acc[p] = (f32x4)(0.f);

    #pragma unroll
    for (int ty = 0; ty < 3; ty++) {
        #pragma unroll
        for (int tx = 0; tx < 3; tx++) {
            const short* ab = slab + (ty * 34 + wm * 16 + lx + tx) * LDSTR + kg * 8;
            const int tap = ty * 3 + tx;
            #pragma unroll
            for (int ch = 0; ch < NCH; ch++) {
                short8v a = *(const short8v*)(ab + ch * 32);
                #pragma unroll
                for (int p = 0; p < OPW; p++) {
                    short8v bf = *(const short8v*)(wbase +
                        (size_t)((tap * NCH + ch) * NOCT + p) * 512);
                    acc[p] = __builtin_amdgcn_mfma_f32_16x16x32_bf16(a, bf, acc[p], 0, 0, 0);
                }
            }
        }
    }

    if (OUTBF16) {
        // raw bf16 -> padded NHWC (borders untouched, stay zero)
        #pragma unroll
        for (int p = 0; p < OPW; p++) {
            const int oc = (wn * OPW + p) * 16 + lx;
            #pragma unroll
            for (int r = 0; r < 4; r++) {
                const int px_x = X0 + wm * 16 + kg * 4 + r;
                dstB[((size_t)b * PADPIX + (size_t)(y + 1) * 130 + px_x + 1) * 64 + oc] =
                    bf16rne(acc[p][r]);
            }
        }
    } else {
        const int ox = X0 + wm * 16 + kg * 4;
        #pragma unroll
        for (int p = 0; p < OPW; p++) {
            const int oc = (wn * OPW + p) * 16 + lx;
            *(f32x4*)(dstF + (((size_t)(b * COUT + oc)) << 14) + (y << 7) + ox) = acc[p];
        }
    }

    // per-wave BN partials: shfl reduce over the 4 kg groups, plain stores
    #pragma unroll
    for (int p = 0; p < OPW; p++) {
        float s = 0.f, q2 = 0.f;
        f32x4 v = acc[p];
        #pragma unroll
        for (int r = 0; r < 4; r++) { s += v[r]; q2 = fmaf(v[r], v[r], q2); }
        s += __shfl_xor(s, 16); q2 += __shfl_xor(q2, 16);
        s += __shfl_xor(s, 32); q2 += __shfl_xor(q2, 32);
        if (l < 16) {
            const int oc = (wn * OPW + p) * 16 + lx;
            float* dp = partials + (((size_t)blockIdx.x * NWM + wm) * 64 + oc) * 2;
            dp[0] = s;
            dp[1] = q2;
        }
    }
}

// ===== reduce 2048 partial pairs per channel -> raw sums (no atomics) ========
__global__ void bnred_kernel(const float* __restrict__ partials,
                             float* __restrict__ statsAcc) {
    int ch = blockIdx.x;                                 // 64 blocks
    const int t = threadIdx.x;
    float s = 0.f, q = 0.f;
    for (int i = t; i < 2048; i += 256) {
        const float* p = partials + ((size_t)i * 64 + ch) * 2;
        s += p[0];
        q += p[1];
    }
    __shared__ float sh[512];
    sh[t] = s;
    sh[256 + t] = q;
    __syncthreads();
    for (int off = 128; off > 0; off >>= 1) {
        if (t < off) {
            sh[t] += sh[t + off];
            sh[256 + t] += sh[256 + t + off];
        }
        __syncthreads();
    }
    if (t == 0) {
        statsAcc[ch * 2] = sh[0];
        statsAcc[ch * 2 + 1] = sh[256];
    }
}

// ===== inline-finalized BN + relu + split o1/o2 -> d_out =====================
__global__ void norm2_kernel(const float4* __restrict__ src,
                             const float* __restrict__ statsAcc,
                             const float* __restrict__ g, const float* __restrict__ beta,
                             float4* __restrict__ out) {
    int idx4 = blockIdx.x * 256 + threadIdx.x;           // over 2*64*4096
    int q = idx4 & 4095;
    int c = (idx4 >> 12) & 63;
    int b = idx4 >> 18;
    float mean = statsAcc[c * 2] * (1.f / 32768.f);
    float var  = statsAcc[c * 2 + 1] * (1.f / 32768.f) - mean * mean;
    float sc = g[c] * rsqrtf(var + 1e-5f);
    float sh = beta[c] - mean * sc;
    float4 v = src[idx4];
    v.x = fmaxf(fmaf(v.x, sc, sh), 0.f);
    v.y = fmaxf(fmaf(v.y, sc, sh), 0.f);
    v.z = fmaxf(fmaf(v.z, sc, sh), 0.f);
    v.w = fmaxf(fmaf(v.w, sc, sh), 0.f);
    int half = c >> 5, cc = c & 31;
    out[(size_t)half * 262144 + (((size_t)(b * 32 + cc)) << 12) + q] = v;
}

extern "C" void kernel_launch(void* const* d_in, const int* in_sizes, int n_in,
                              void* d_out, int out_size, void* d_ws, size_t ws_size,
                              hipStream_t stream) {
    const float* x1 = (const float*)d_in[0];
    // d_in[1] (x1_) is unused by the reference
    const float* x2 = (const float*)d_in[2];
    const float* Wq = (const float*)d_in[3];
    const float* bq = (const float*)d_in[4];
    const float* Wk = (const float*)d_in[5];
    const float* bk = (const float*)d_in[6];
    const float* Wv = (const float*)d_in[7];
    const float* bv = (const float*)d_in[8];
    const float* W1 = (const float*)d_in[9];
    const float* g1 = (const float*)d_in[10];
    const float* b1 = (const float*)d_in[11];
    const float* W2 = (const float*)d_in[12];
    const float* g2 = (const float*)d_in[13];
    const float* b2 = (const float*)d_in[14];
    float* out = (float*)d_out;
    float* ws = (float*)d_ws;

    // workspace layout (float offsets)
    float* c1out    = ws;                        // [2][64][HW] fp32     (2,097,152)
    float* stacc    = ws + 2097152;              // 256 raw sums (s1 @ +0, s2 @ +128)
    short* hcatN    = (short*)(ws + 2097408);    // [2][PADPIX][128] bf16 (2,163,200 f)
    short* h1N      = (short*)(ws + 4260608);    // [2][PADPIX][64]  bf16 (1,081,600 f)
    short* Wb1      = (short*)(ws + 5342208);    // 73728 shorts = 36864 f
    short* Wb2      = (short*)(ws + 5379072);    // 36864 shorts = 18432 f
    short* Wbk      = (short*)(ws + 5397504);    // 9216 shorts  =  4608 f
    float* partials = ws + 5402112;              // 1024*2*64*2 = 262,144 f (1 MB)

    // K1: weight prep + border zeroing
    k1_kernel<<<565, 256, 0, stream>>>(W1, W2, Wk, Wb1, Wb2, Wbk, hcatN, h1N);

    // front: upsample + Kf conv + qconv + gate, fused -> hcatN (both halves)
    front_kernel<<<1024, 256, 0, stream>>>(x1, Wbk, bk, Wq, bq, x2, Wv, bv, hcatN);

    // conv1 128->64: raw bf16 -> padded NHWC h1N, fused partial stats
    convmfma_kernel<128, 136, 128, 64, 2, 2, true, false><<<1024, 256, 0, stream>>>(
        hcatN, Wb1, nullptr, h1N, nullptr, nullptr, nullptr, partials);
    bnred_kernel<<<64, 256, 0, stream>>>(partials, stacc);

    // conv2 64->64: BN1+relu applied inline while staging h1N; fp32 out
    convmfma_kernel<64, 72, 64, 64, 2, 2, false, true><<<1024, 256, 0, stream>>>(
        h1N, Wb2, c1out, nullptr, stacc, g1, b1, partials);
    bnred_kernel<<<64, 256, 0, stream>>>(partials, stacc + 128);

    // BN2 finalize + relu + split -> d_out
    norm2_kernel<<<2048, 256, 0, stream>>>((const float4*)c1out, stacc + 128, g2, b2,
                                           (float4*)out);
}

// Round 20
// 69.533 us; speedup vs baseline: 12.8435x; 1.0085x over previous
//
#include <hip/hip_runtime.h>

#define HW 16384        // 128*128
#define PADPIX 16900    // 130*130 padded pixel count

typedef __attribute__((ext_vector_type(8))) short short8v;
typedef __attribute__((ext_vector_type(4))) float f32x4;

__device__ inline short bf16rne(float x) {
    unsigned u = __float_as_uint(x);
    unsigned r = (u + 0x7fffu + ((u >> 16) & 1u)) >> 16;
    return (short)r;
}
__device__ inline float bf16tof(short s) {
    return __uint_as_float(((unsigned)(unsigned short)s) << 16);
}

// padded-pixel index for border element j (j in 0..515)
__device__ inline int border_pp(int j) {
    if (j < 130) return j;                          // row 0
    if (j < 260) return 129 * 130 + (j - 130);      // row 129
    if (j < 388) return (j - 259) * 130;            // col 0, rows 1..128
    return (j - 387) * 130 + 129;                   // col 129, rows 1..128
}

// ===== K1: weight prep (0..467) + borders (468..564) =========================
__global__ __launch_bounds__(256) void k1_kernel(
    const float* __restrict__ W1, const float* __restrict__ W2,
    const float* __restrict__ Wk,
    short* __restrict__ Wb1, short* __restrict__ Wb2, short* __restrict__ Wbk,
    short* __restrict__ hcatN, short* __restrict__ h1N)
{
    int bid = blockIdx.x;
    const int t = threadIdx.x;
    if (bid < 468) {
        const float* W; short* Wb; int CIN, COUT, idx;
        if (bid < 288)      { W = W1; Wb = Wb1; CIN = 128; COUT = 64; idx = bid * 256 + t; }
        else if (bid < 432) { W = W2; Wb = Wb2; CIN = 64;  COUT = 64; idx = (bid - 288) * 256 + t; }
        else                { W = Wk; Wb = Wbk; CIN = 64;  COUT = 16; idx = (bid - 432) * 256 + t; }
        int NOCT = COUT >> 4, NCH = CIN >> 5;
        int total = 9 * NCH * NOCT * 512;
        if (idx >= total) return;
        int j = idx & 7, l = (idx >> 3) & 63;
        int rest = idx >> 9;
        int oct = rest % NOCT; rest /= NOCT;
        int ch = rest % NCH;
        int tap = rest / NCH;
        int o = oct * 16 + (l & 15);
        int c = ch * 32 + (l >> 4) * 8 + j;
        Wb[idx] = bf16rne(W[((size_t)o * CIN + c) * 9 + tap]);
        return;
    }
    // ---- zero borders of hcatN (16512 int4) and h1N (8256 int4) ----
    int t2 = (bid - 468) * 256 + t;
    const int4 z = make_int4(0, 0, 0, 0);
    if (t2 < 16512) {
        int px = t2 >> 4, q = t2 & 15;
        int b = px >= 516; int j = px - b * 516;
        int pp = border_pp(j);
        ((int4*)hcatN)[((size_t)b * PADPIX + pp) * 16 + q] = z;
    } else if (t2 < 24768) {
        int idx = t2 - 16512;
        int px = idx >> 3, q = idx & 7;
        int b = px >= 516; int j = px - b * 516;
        int pp = border_pp(j);
        ((int4*)h1N)[((size_t)b * PADPIX + pp) * 8 + q] = z;
    }
}

// ===== front: upsample -> (Kf MFMA || qconv) -> gate -> hcatN, all in LDS ====
#define UPSTR 72                 // ch-stride of upB in shorts (16B-aligned)
#define UPROW (34 * UPSTR)       // shorts per upB row (34 lpx)
__global__ __launch_bounds__(256) void front_kernel(
    const float* __restrict__ x1, const short* __restrict__ Wbk,
    const float* __restrict__ bk, const float* __restrict__ Wq,
    const float* __restrict__ bq, const float* __restrict__ x2,
    const float* __restrict__ Wv, const float* __restrict__ bv,
    short* __restrict__ hcatN)
{
    __shared__ __align__(16) short upB[3 * UPROW];   // [r][lpx 0..33][ch 0..63]
    __shared__ float kfs[16 * 33];                   // [k][px 0..31], stride 33
    __shared__ float qbuf[32 * 65];                  // [px][ch], stride 65
    __shared__ int tr[32 * 33];                      // [chpair][px], stride 33
    int bid = blockIdx.x;
    const int xq = bid & 3;
    const int y = (bid >> 2) & 127;
    const int b = bid >> 9;
    const int t = threadIdx.x;
    const int X0 = xq * 32;

    // ---- phase 1: upsample rows y-1..y+1 (bf16) into upB, zeros outside ----
    {
        const int px1 = t & 31, cg1 = t >> 5;        // 32 px x 8 ch-groups
        const int gx = X0 + px1;
        float fx = (float)(gx * 63) / 127.f;
        int x0 = (int)fx; float wx = fx - (float)x0; int x1i = min(x0 + 1, 63);
        #pragma unroll
        for (int r = 0; r < 3; r++) {
            int ry = y + r - 1;
            bool rv = ((unsigned)ry < 128u);
            int ryc = rv ? ry : 0;
            float fy = (float)(ryc * 63) / 127.f;
            int y0 = (int)fy; float wy = fy - (float)y0; int y1 = min(y0 + 1, 63);
            int pk[4];
            #pragma unroll
            for (int jj = 0; jj < 4; jj++) {
                unsigned lohi[2];
                #pragma unroll
                for (int h = 0; h < 2; h++) {
                    int ch = cg1 * 8 + jj * 2 + h;
                    float v = 0.f;
                    if (rv) {
                        const float* sp = x1 + ((size_t)(b * 64 + ch) << 12);
                        float v00 = sp[(y0 << 6) + x0], v01 = sp[(y0 << 6) + x1i];
                        float v10 = sp[(y1 << 6) + x0], v11 = sp[(y1 << 6) + x1i];
                        float top = v00 * (1.f - wx) + v01 * wx;
                        float bot = v10 * (1.f - wx) + v11 * wx;
                        v = top * (1.f - wy) + bot * wy;
                    }
                    lohi[h] = (unsigned)(unsigned short)bf16rne(v);
                }
                pk[jj] = (int)(lohi[0] | (lohi[1] << 16));
            }
            *(int4*)(upB + r * UPROW + (px1 + 1) * UPSTR + cg1 * 8) =
                make_int4(pk[0], pk[1], pk[2], pk[3]);
        }
        if (t < 48) {                                // halo: r x side x cg
            int r = t >> 4, side = (t >> 3) & 1, cg = t & 7;
            int gxh = X0 + (side ? 32 : -1);
            int lpx = side ? 33 : 0;
            int ry = y + r - 1;
            bool v_ok = ((unsigned)ry < 128u) && ((unsigned)gxh < 128u);
            int ryc = ((unsigned)ry < 128u) ? ry : 0;
            float fy = (float)(ryc * 63) / 127.f;
            int y0 = (int)fy; float wy = fy - (float)y0; int y1 = min(y0 + 1, 63);
            int gxc = min(max(gxh, 0), 127);
            float fxh = (float)(gxc * 63) / 127.f;
            int hx0 = (int)fxh; float hwx = fxh - (float)hx0; int hx1 = min(hx0 + 1, 63);
            int pk[4];
            #pragma unroll
            for (int jj = 0; jj < 4; jj++) {
                unsigned lohi[2];
                #pragma unroll
                for (int h = 0; h < 2; h++) {
                    int ch = cg * 8 + jj * 2 + h;
                    float v = 0.f;
                    if (v_ok) {
                        const float* sp = x1 + ((size_t)(b * 64 + ch) << 12);
                        float v00 = sp[(y0 << 6) + hx0], v01 = sp[(y0 << 6) + hx1];
                        float v10 = sp[(y1 << 6) + hx0], v11 = sp[(y1 << 6) + hx1];
                        float top = v00 * (1.f - hwx) + v01 * hwx;
                        float bot = v10 * (1.f - hwx) + v11 * hwx;
                        v = top * (1.f - wy) + bot * wy;
                    }
                    lohi[h] = (unsigned)(unsigned short)bf16rne(v);
                }
                pk[jj] = (int)(lohi[0] | (lohi[1] << 16));
            }
            *(int4*)(upB + r * UPROW + lpx * UPSTR + cg * 8) =
                make_int4(pk[0], pk[1], pk[2], pk[3]);
        }
    }
    __syncthreads();

    // ---- phase 2: waves 0-1: Kf MFMA (16 px each); waves 2-3: qconv --------
    {
        const int w = t >> 6, l = t & 63;
        if (w < 2) {
            const int lx = l & 15, kg = l >> 4;
            const short* wbase = Wbk + (size_t)l * 8;
            f32x4 acc = (f32x4)(0.f);
            #pragma unroll
            for (int ty = 0; ty < 3; ty++) {
                #pragma unroll
                for (int tx = 0; tx < 3; tx++) {
                    const short* ab = upB + ty * UPROW + (size_t)(w * 16 + lx + tx) * UPSTR;
                    #pragma unroll
                    for (int ch = 0; ch < 2; ch++) {
                        short8v a = *(const short8v*)(ab + kg * 8 + ch * 32);
                        short8v bf = *(const short8v*)(wbase +
                            (size_t)((ty * 3 + tx) * 2 + ch) * 512);
                        acc = __builtin_amdgcn_mfma_f32_16x16x32_bf16(a, bf, acc, 0, 0, 0);
                    }
                }
            }
            float bb = bk[lx];
            #pragma unroll
            for (int r = 0; r < 4; r++)
                kfs[lx * 33 + (w * 16 + kg * 4 + r)] = fmaxf(acc[r] + bb, 0.f);
        } else {
            // depthwise qconv, ch-major sliding window (conflict-free LDS reads)
            const int ch = l;
            const int px0 = (w - 2) * 16;
            const float* wqp = Wq + ch * 9;
            float wq[9];
            #pragma unroll
            for (int i = 0; i < 9; i++) wq[i] = wqp[i];
            float bqc = bq[ch];
            float a0[3], a1[3];
            #pragma unroll
            for (int r = 0; r < 3; r++) {
                a0[r] = bf16tof(upB[r * UPROW + px0 * UPSTR + ch]);
                a1[r] = bf16tof(upB[r * UPROW + (px0 + 1) * UPSTR + ch]);
            }
            for (int p = 0; p < 16; p++) {
                float a2[3];
                #pragma unroll
                for (int r = 0; r < 3; r++)
                    a2[r] = bf16tof(upB[r * UPROW + (px0 + p + 2) * UPSTR + ch]);
                float q = bqc;
                #pragma unroll
                for (int r = 0; r < 3; r++)
                    q = fmaf(a0[r], wq[r * 3 + 0],
                        fmaf(a1[r], wq[r * 3 + 1], fmaf(a2[r], wq[r * 3 + 2], q)));
                qbuf[(px0 + p) * 65 + ch] = fmaxf(q, 0.f);
                #pragma unroll
                for (int r = 0; r < 3; r++) { a0[r] = a1[r]; a1[r] = a2[r]; }
            }
        }
    }
    __syncthreads();

    // ---- phase 3: softmax gate, 32 px x 64 ch -------------------------------
    {
        const int px = t & 31, cg = t >> 5;
        const int x = X0 + px;
        float kv[16];
        #pragma unroll
        for (int k = 0; k < 16; k++) kv[k] = kfs[k * 33 + px];
        float kvmax = kv[0];
        #pragma unroll
        for (int k = 1; k < 16; k++) kvmax = fmaxf(kvmax, kv[k]);
        float wvv[16], bvv[16];
        #pragma unroll
        for (int k = 0; k < 16; k++) { wvv[k] = Wv[k]; bvv[k] = bv[k]; }
        float xvv[8], qv[8];
        #pragma unroll
        for (int j = 0; j < 8; j++) {
            xvv[j] = x2[((size_t)(b * 64 + cg * 8 + j) << 14) + (y << 7) + x];
            qv[j] = qbuf[px * 65 + cg * 8 + j];
        }
        #pragma unroll
        for (int jj = 0; jj < 4; jj++) {
            int gpk = 0;
            #pragma unroll
            for (int h = 0; h < 2; h++) {
                const int j = jj * 2 + h;
                float q = qv[j];
                float mx = q * kvmax;                // q,kv >= 0 => exact max
                float den = 0.f, num = 0.f;
                #pragma unroll
                for (int k = 0; k < 16; k++) {
                    float e = __expf(fmaf(q, kv[k], -mx));
                    den += e;
                    float V = fmaxf(fmaf(xvv[j], wvv[k], bvv[k]), 0.f);
                    num = fmaf(e, V, num);
                }
                unsigned u = (unsigned)(unsigned short)bf16rne(num / den);
                gpk |= (int)(u << (h * 16));
            }
            tr[(cg * 4 + jj) * 33 + px] = gpk;
        }
    }
    __syncthreads();

    // ---- phase 4: coalesced writes: gate -> ch 0..63, upB row1 -> ch 64..127
    {
        const int px4 = t >> 3, cq = t & 7;
        int pp = (y + 1) * 130 + X0 + px4 + 1;
        int wd[4];
        #pragma unroll
        for (int i = 0; i < 4; i++) wd[i] = tr[(cq * 4 + i) * 33 + px4];
        int* dpL = (int*)hcatN + ((size_t)b * PADPIX + pp) * 64 + cq * 4;
        *(int4*)dpL = make_int4(wd[0], wd[1], wd[2], wd[3]);
        const short* us = upB + UPROW + (size_t)(px4 + 1) * UPSTR + cq * 8;
        int4 u = *(const int4*)us;
        int* dpU = (int*)hcatN + ((size_t)b * PADPIX + pp) * 64 + 32 + cq * 4;
        *(int4*)dpU = u;
    }
}

// ===== MFMA implicit-GEMM 3x3 conv, LDS-staged A-slab, raw-bf16 out ==========
// PADOUT: write to padded NHWC (borders stay zero); else flat NHWC [b][HW][64].
// INBN: apply BN(scale,shift)+relu inline while staging (borders forced to 0).
template<int PSTR, int LDSTR, int CIN, int COUT, int NWN, int OPW,
         bool PADOUT, bool INBN>
__global__ __launch_bounds__(256) void convmfma_kernel(
    const short* __restrict__ actN, const short* __restrict__ Wb,
    short* __restrict__ dstB,
    const float* __restrict__ statsAcc,
    const float* __restrict__ g, const float* __restrict__ beta,
    float* __restrict__ partials)
{
    constexpr int NCH = CIN / 32, NOCT = COUT / 16, NWM = 4 / NWN;
    constexpr int EXT = NWM * 16;
    constexpr int SEG = 128 / EXT;
    __shared__ __align__(16) short slab[3 * 34 * LDSTR];
    __shared__ float scsh[INBN ? 128 : 2];
    const int t = threadIdx.x;
    const int w = t >> 6, l = t & 63;
    const int wn = w % NWN, wm = w / NWN;
    int bid = blockIdx.x;
    const int xseg = bid % SEG; bid /= SEG;
    const int y = bid & 127;
    const int b = bid >> 7;
    const int lx = l & 15, kg = l >> 4;
    const int X0 = xseg * EXT;

    if (INBN) {
        if (t < 64) {
            float mean = statsAcc[t * 2] * (1.f / 32768.f);
            float var  = statsAcc[t * 2 + 1] * (1.f / 32768.f) - mean * mean;
            float sc = g[t] * rsqrtf(var + 1e-5f);
            scsh[t] = sc;
            scsh[64 + t] = beta[t] - mean * sc;
        }
        __syncthreads();
    }

    // ---- stage 3 rows x 34 px x CIN into LDS (all in-bounds of padded buf) --
    constexpr int ROWI4 = 34 * PSTR / 8;             // int4 per slab row
    constexpr int PXI4 = PSTR / 8;                   // int4 per pixel (pow2)
    #pragma unroll
    for (int r = 0; r < 3; r++) {
        const int prow = y + r;                      // padded row 0..129
        const bool rowb = (prow == 0) || (prow == 129);
        const int4* src = (const int4*)(actN +
            ((size_t)b * PADPIX + (size_t)prow * 130 + X0) * PSTR);
        for (int i = t; i < ROWI4; i += 256) {
            int p = i / PXI4, cq = i % PXI4;
            int4 v = src[i];
            if (INBN) {
                int pcol = X0 + p;                   // padded col 0..129
                if (rowb || pcol == 0 || pcol == 129) {
                    v = make_int4(0, 0, 0, 0);
                } else {
                    int ch0 = cq * 8;
                    int* vw = (int*)&v;
                    #pragma unroll
                    for (int wd = 0; wd < 4; wd++) {
                        int c0 = ch0 + wd * 2, c1 = c0 + 1;
                        float lo = bf16tof((short)(vw[wd] & 0xFFFF));
                        float hi = bf16tof((short)((unsigned)vw[wd] >> 16));
                        lo = fmaxf(fmaf(lo, scsh[c0], scsh[64 + c0]), 0.f);
                        hi = fmaxf(fmaf(hi, scsh[c1], scsh[64 + c1]), 0.f);
                        unsigned ulo = (unsigned)(unsigned short)bf16rne(lo);
                        unsigned uhi = (unsigned)(unsigned short)bf16rne(hi);
                        vw[wd] = (int)(ulo | (uhi << 16));
                    }
                }
            }
            *(int4*)(slab + (r * 34 + p) * LDSTR + cq * 8) = v;
        }
    }
    __syncthreads();

    const short* wbase = Wb + (size_t)(wn * OPW) * 512 + (size_t)l * 8;

    f32x4 acc[OPW];
    #pragma unroll
    for (int p = 0; p < OPW; p++) acc[p] = (f32x4)(0.f);

    #pragma unroll
    for (int ty = 0; ty < 3; ty++) {
        #pragma unroll
        for (int tx = 0; tx < 3; tx++) {
            const short* ab = slab + (ty * 34 + wm * 16 + lx + tx) * LDSTR + kg * 8;
            const int tap = ty * 3 + tx;
            #pragma unroll
            for (int ch = 0; ch < NCH; ch++) {
                short8v a = *(const short8v*)(ab + ch * 32);
                #pragma unroll
                for (int p = 0; p < OPW; p++) {
                    short8v bf = *(const short8v*)(wbase +
                        (size_t)((tap * NCH + ch) * NOCT + p) * 512);
                    acc[p] = __builtin_amdgcn_mfma_f32_16x16x32_bf16(a, bf, acc[p], 0, 0, 0);
                }
            }
        }
    }

    // raw bf16 epilogue (unnormalized); PADOUT keeps zero borders intact
    #pragma unroll
    for (int p = 0; p < OPW; p++) {
        const int oc = (wn * OPW + p) * 16 + lx;
        #pragma unroll
        for (int r = 0; r < 4; r++) {
            const int px_x = X0 + wm * 16 + kg * 4 + r;
            size_t pix = PADOUT
                ? ((size_t)b * PADPIX + (size_t)(y + 1) * 130 + px_x + 1)
                : ((size_t)b * HW + (size_t)y * 128 + px_x);
            dstB[pix * COUT + oc] = bf16rne(acc[p][r]);
        }
    }

    // per-wave BN partials: shfl reduce over the 4 kg groups, plain stores
    #pragma unroll
    for (int p = 0; p < OPW; p++) {
        float s = 0.f, q2 = 0.f;
        f32x4 v = acc[p];
        #pragma unroll
        for (int r = 0; r < 4; r++) { s += v[r]; q2 = fmaf(v[r], v[r], q2); }
        s += __shfl_xor(s, 16); q2 += __shfl_xor(q2, 16);
        s += __shfl_xor(s, 32); q2 += __shfl_xor(q2, 32);
        if (l < 16) {
            const int oc = (wn * OPW + p) * 16 + lx;
            float* dp = partials + (((size_t)blockIdx.x * NWM + wm) * 64 + oc) * 2;
            dp[0] = s;
            dp[1] = q2;
        }
    }
}

// ===== reduce 2048 partial pairs per channel -> raw sums (no atomics) ========
__global__ void bnred_kernel(const float* __restrict__ partials,
                             float* __restrict__ statsAcc) {
    int ch = blockIdx.x;                                 // 64 blocks
    const int t = threadIdx.x;
    float s = 0.f, q = 0.f;
    for (int i = t; i < 2048; i += 256) {
        const float* p = partials + ((size_t)i * 64 + ch) * 2;
        s += p[0];
        q += p[1];
    }
    __shared__ float sh[512];
    sh[t] = s;
    sh[256 + t] = q;
    __syncthreads();
    for (int off = 128; off > 0; off >>= 1) {
        if (t < off) {
            sh[t] += sh[t + off];
            sh[256 + t] += sh[256 + t + off];
        }
        __syncthreads();
    }
    if (t == 0) {
        statsAcc[ch * 2] = sh[0];
        statsAcc[ch * 2 + 1] = sh[256];
    }
}

// ===== BN2 finalize + relu on raw-bf16 NHWC, transpose, split -> d_out =======
// block = (b, 32-px chunk); phase A: NHWC int4 read + BN -> LDS[ch][px];
// phase B: LDS row read -> coalesced fp32 NCHW split writes.
__global__ __launch_bounds__(256) void norm2_kernel(
    const short* __restrict__ h2N, const float* __restrict__ statsAcc,
    const float* __restrict__ g, const float* __restrict__ beta,
    float* __restrict__ out)
{
    __shared__ float lds[64 * 33];
    __shared__ float scsh[128];
    int bid = blockIdx.x;
    const int chunk = bid & 511;                         // 512 chunks x 32 px
    const int b = bid >> 9;
    const int t = threadIdx.x;
    const int P0 = chunk * 32;
    if (t < 64) {
        float mean = statsAcc[t * 2] * (1.f / 32768.f);
        float var  = statsAcc[t * 2 + 1] * (1.f / 32768.f) - mean * mean;
        float sc = g[t] * rsqrtf(var + 1e-5f);
        scsh[t] = sc;
        scsh[64 + t] = beta[t] - mean * sc;
    }
    __syncthreads();
    {
        const int px = t >> 3, cq = t & 7;
        const short* sp = h2N + ((size_t)b * HW + P0 + px) * 64 + cq * 8;
        int4 v = *(const int4*)sp;
        const int* vw = (const int*)&v;
        #pragma unroll
        for (int wd = 0; wd < 4; wd++) {
            int c0 = cq * 8 + wd * 2, c1 = c0 + 1;
            float lo = bf16tof((short)(vw[wd] & 0xFFFF));
            float hi = bf16tof((short)((unsigned)vw[wd] >> 16));
            lds[c0 * 33 + px] = fmaxf(fmaf(lo, scsh[c0], scsh[64 + c0]), 0.f);
            lds[c1 * 33 + px] = fmaxf(fmaf(hi, scsh[c1], scsh[64 + c1]), 0.f);
        }
    }
    __syncthreads();
    {
        const int c = t >> 2, qx = t & 3;
        const float* r = lds + c * 33 + qx * 8;
        float4 o0, o1;
        o0.x = r[0]; o0.y = r[1]; o0.z = r[2]; o0.w = r[3];
        o1.x = r[4]; o1.y = r[5]; o1.z = r[6]; o1.w = r[7];
        int half = c >> 5, cc = c & 31;
        float* dp = out + (size_t)half * 1048576 + (((size_t)(b * 32 + cc)) << 14)
                  + P0 + qx * 8;
        *(float4*)dp = o0;
        *(float4*)(dp + 4) = o1;
    }
}

extern "C" void kernel_launch(void* const* d_in, const int* in_sizes, int n_in,
                              void* d_out, int out_size, void* d_ws, size_t ws_size,
                              hipStream_t stream) {
    const float* x1 = (const float*)d_in[0];
    // d_in[1] (x1_) is unused by the reference
    const float* x2 = (const float*)d_in[2];
    const float* Wq = (const float*)d_in[3];
    const float* bq = (const float*)d_in[4];
    const float* Wk = (const float*)d_in[5];
    const float* bk = (const float*)d_in[6];
    const float* Wv = (const float*)d_in[7];
    const float* bv = (const float*)d_in[8];
    const float* W1 = (const float*)d_in[9];
    const float* g1 = (const float*)d_in[10];
    const float* b1 = (const float*)d_in[11];
    const float* W2 = (const float*)d_in[12];
    const float* g2 = (const float*)d_in[13];
    const float* b2 = (const float*)d_in[14];
    float* out = (float*)d_out;
    float* ws = (float*)d_ws;

    // workspace layout (float offsets)
    float* stacc    = ws;                        // 256 raw sums (s1 @ +0, s2 @ +128)
    short* h2N      = (short*)(ws + 256);        // [2][HW][64] bf16  (1,048,576 f)
    short* hcatN    = (short*)(ws + 1048832);    // [2][PADPIX][128] bf16 (2,163,200 f)
    short* h1N      = (short*)(ws + 3212032);    // [2][PADPIX][64]  bf16 (1,081,600 f)
    short* Wb1      = (short*)(ws + 4293632);    // 73728 shorts = 36864 f
    short* Wb2      = (short*)(ws + 4330496);    // 36864 shorts = 18432 f
    short* Wbk      = (short*)(ws + 4348928);    // 9216 shorts  =  4608 f
    float* partials = ws + 4353536;              // 1024*2*64*2 = 262,144 f (1 MB)

    // K1: weight prep + border zeroing
    k1_kernel<<<565, 256, 0, stream>>>(W1, W2, Wk, Wb1, Wb2, Wbk, hcatN, h1N);

    // front: upsample + Kf conv + qconv + gate, fused -> hcatN (both halves)
    front_kernel<<<1024, 256, 0, stream>>>(x1, Wbk, bk, Wq, bq, x2, Wv, bv, hcatN);

    // conv1 128->64: raw bf16 -> padded NHWC h1N, fused partial stats
    convmfma_kernel<128, 136, 128, 64, 2, 2, true, false><<<1024, 256, 0, stream>>>(
        hcatN, Wb1, h1N, nullptr, nullptr, nullptr, partials);
    bnred_kernel<<<64, 256, 0, stream>>>(partials, stacc);

    // conv2 64->64: BN1+relu inline while staging; raw bf16 -> flat NHWC h2N
    convmfma_kernel<64, 72, 64, 64, 2, 2, false, true><<<1024, 256, 0, stream>>>(
        h1N, Wb2, h2N, stacc, g1, b1, partials);
    bnred_kernel<<<64, 256, 0, stream>>>(partials, stacc + 128);

    // BN2 finalize + relu + transpose + split -> d_out
    norm2_kernel<<<1024, 256, 0, stream>>>(h2N, stacc + 128, g2, b2, out);
}